// Round 1
// baseline (319.083 us; speedup 1.0000x reference)
//
#include <hip/hip_runtime.h>
#include <stdint.h>

typedef uint16_t u16;
typedef uint32_t u32;
typedef __bf16 bf16_t;
typedef __bf16 bf16x8 __attribute__((ext_vector_type(8)));
typedef __bf16 bf16x4 __attribute__((ext_vector_type(4)));
typedef float  f32x4  __attribute__((ext_vector_type(4)));

#define MFMA16(a,b,c) __builtin_amdgcn_mfma_f32_16x16x32_bf16(a,b,c,0,0,0)

static __device__ __forceinline__ u16 f2bf(float f){
  union { bf16_t b; u16 u; } cv; cv.b = (bf16_t)f; return cv.u;
}
static __device__ __forceinline__ u32 pack2(float a, float b){
  return (u32)f2bf(a) | ((u32)f2bf(b) << 16);
}

// ---------------- K0: exp(bias) table [dh+31][h][dw+31] (63*512 f32) ----------------------
__global__ __launch_bounds__(256) void k_bias_setup(
    const float* __restrict__ dist_bias, const float* __restrict__ dir_bias,
    float* __restrict__ ebtab)
{
  int tid = blockIdx.x*256 + threadIdx.x;
  if (tid >= 63*63) return;
  int dhi = tid / 63, dwi = tid % 63;
  int dh = dhi - 31, dw = dwi - 31;
  int r2 = dh*dh + dw*dw;
  int dist = (int)sqrtf((float)r2);
  if (dist > 59) dist = 59;
  int dir;
  if (dh==0 && dw==0)      dir = 0;
  else if (dh==0)          dir = (dw>0) ? 8  : 0;
  else if (dw==0)          dir = (dh>0) ? 12 : 4;
  else if (dh==dw)         dir = (dh>0) ? 10 : 2;
  else if (dh==-dw)        dir = (dh>0) ? 14 : 6;
  else {
    float ang = atan2f((float)dh, (float)dw) + 3.14159265358979323846f;
    int k = (int)floorf(ang * 2.5464790894703254f);
    dir = k & 15;
  }
  for (int h=0; h<8; h++){
    ebtab[dhi*512 + h*64 + dwi] = expf(dist_bias[dist*8+h] + dir_bias[dir*8+h]);
  }
}

// ---------------- K1: fused Q/K/V projection. blockIdx.y selects matrix. ------------------
// C[8192,256] = X @ W^T + b (f32 in, bf16 MFMA, bf16 out), reg-prefetch double-buffered.
__global__ __launch_bounds__(256) void k_proj3(
    const float* __restrict__ X,
    const float* __restrict__ Wq, const float* __restrict__ Bq,
    const float* __restrict__ Wk, const float* __restrict__ Bk,
    const float* __restrict__ Wv, const float* __restrict__ Bvv,
    u16* __restrict__ Qo, u16* __restrict__ Ko, u16* __restrict__ Vo,
    float qscale)
{
  const float* W; const float* Bv; u16* Out; float scale; int vt_mode;
  if (blockIdx.y == 0)      { W = Wq; Bv = Bq;  Out = Qo; scale = qscale; vt_mode = 0; }
  else if (blockIdx.y == 1) { W = Wk; Bv = Bk;  Out = Ko; scale = 1.0f;   vt_mode = 0; }
  else                      { W = Wv; Bv = Bvv; Out = Vo; scale = 1.0f;   vt_mode = 1; }

  __shared__ bf16_t Xs[32*40];
  __shared__ bf16_t Wsh[256*40];
  __shared__ float  Cs[32*260];
  const int t = threadIdx.x;
  const int wv = t>>6, ln = t&15, qd = (t&63)>>4;
  const int wm = wv & 1, wn = wv >> 1;
  const int m0 = blockIdx.x * 32;

  f32x4 z4 = {0.0f,0.0f,0.0f,0.0f};
  f32x4 acc[8];
  #pragma unroll
  for (int i=0;i<8;i++) acc[i] = z4;

  f32x4 XR; f32x4 WR[8];
  XR = *(const f32x4*)(X + (size_t)(m0 + (t>>3))*256 + (t&7)*4);
  #pragma unroll
  for (int j=0;j<8;j++)
    WR[j] = *(const f32x4*)(W + (size_t)((t>>3)+32*j)*256 + (t&7)*4);

  for (int kt=0; kt<8; kt++){
    __syncthreads();
    { int m = t>>3, k0 = (t&7)*4;
      uint2 pk; pk.x = pack2(XR[0], XR[1]); pk.y = pack2(XR[2], XR[3]);
      *(uint2*)&Xs[m*40 + k0] = pk;
    }
    #pragma unroll
    for (int j=0;j<8;j++){
      int n = (t>>3) + 32*j, k0 = (t&7)*4;
      uint2 pk; pk.x = pack2(WR[j][0], WR[j][1]); pk.y = pack2(WR[j][2], WR[j][3]);
      *(uint2*)&Wsh[n*40 + k0] = pk;
    }
    __syncthreads();
    if (kt < 7){
      XR = *(const f32x4*)(X + (size_t)(m0 + (t>>3))*256 + (kt+1)*32 + (t&7)*4);
      #pragma unroll
      for (int j=0;j<8;j++)
        WR[j] = *(const f32x4*)(W + (size_t)((t>>3)+32*j)*256 + (kt+1)*32 + (t&7)*4);
    }
    bf16x8 a = *(const bf16x8*)&Xs[(wm*16+ln)*40 + qd*8];
    #pragma unroll
    for (int ni=0;ni<8;ni++){
      bf16x8 bb = *(const bf16x8*)&Wsh[(wn*128 + ni*16 + ln)*40 + qd*8];
      acc[ni] = MFMA16(a, bb, acc[ni]);
    }
  }
  __syncthreads();
  #pragma unroll
  for (int ni=0;ni<8;ni++){
    const int col = wn*128 + ni*16 + ln;
    const float bias = Bv[col];
    #pragma unroll
    for (int r=0;r<4;r++){
      Cs[(wm*16 + qd*4 + r)*260 + col] = (acc[ni][r] + bias) * scale;
    }
  }
  __syncthreads();
  if (!vt_mode){
    int row = t>>3, c0 = (t&7)*32;
    u16* op = Out + (size_t)(m0+row)*256 + c0;
    #pragma unroll
    for (int i=0;i<4;i++){
      f32x4 v0 = *(const f32x4*)&Cs[row*260 + c0 + i*8];
      f32x4 v1 = *(const f32x4*)&Cs[row*260 + c0 + i*8 + 4];
      union { u16 h[8]; uint4 v; } pk;
      #pragma unroll
      for (int e=0;e<4;e++){ pk.h[e] = f2bf(v0[e]); pk.h[4+e] = f2bf(v1[e]); }
      *(uint4*)(op + i*8) = pk.v;
    }
  } else {
    const int n = t;
    const int b = m0 >> 10, s0 = m0 & 1023;
    u16* op = Out + (size_t)(b*256 + n)*1024 + s0;
    #pragma unroll
    for (int i=0;i<4;i++){
      union { u16 h[8]; uint4 v; } pk;
      #pragma unroll
      for (int e=0;e<8;e++) pk.h[e] = f2bf(Cs[(i*8+e)*260 + n]);
      *(uint4*)(op + i*8) = pk.v;
    }
  }
}

// ---------------- K2: fused attention: ctx (biased softmax @ V) + attn_w (plain) ----------
// Pass 1: unnormalized-PV with both denominators. Pass 2: plain probs -> attn_w.
// Reg-prefetch double-buffered staging; conflict-free Ks stage map; 4-replica ebs.
__global__ __launch_bounds__(256) void k_attn_fused(
    const u16* __restrict__ Qg, const u16* __restrict__ Kg,
    const u16* __restrict__ Vtg, const float* __restrict__ ebtab,
    u16* __restrict__ ctx, float* __restrict__ AW)
{
  __shared__ bf16_t Ks[32*264];            // 16896 B
  __shared__ __align__(16) char uvt[22528];// pass1: Vt bf16[256*44]; pass2: awp f32[4*528]
  __shared__ bf16_t Ps[4][16*40];          // 5120 B
  __shared__ float  ebs[4*532];            // 8512 B: 4 replicas, stride 532 (conflict-free reads)
  bf16_t* Vt  = (bf16_t*)uvt;
  float*  awp = (float*)uvt;

  const int t  = threadIdx.x;
  const int wv = t >> 6;
  const int ln = t & 15;
  const int qd = (t & 63) >> 4;
  const int b  = blockIdx.y;
  const int qt = blockIdx.x;
  const int qh_img = qt >> 1;
  const int qw0 = (qt & 1) * 16;

  const u16* Qb  = Qg  + (size_t)(b*1024 + qt*16) * 256;
  const u16* Kb  = Kg  + (size_t)b * 1024 * 256;
  const u16* Vtb = Vtg + (size_t)b * 256 * 1024;

  // staging coordinates
  const int srow = t >> 5;          // K stage: base row 0..7
  const int scol = (t & 31) * 8;    // K stage: col in u16 (16B chunks)
  const int vrow = t >> 3;          // Vt stage
  const int vcol = (t & 7) * 4;
  const int erow = (t & 127) * 4;   // ebs stage (dwords)
  const int erep = t >> 7;

  f32x4 z4 = {0.0f,0.0f,0.0f,0.0f};

  bf16x8 aq[2];
  aq[0] = *(const bf16x8*)(Qb + ln*256 + wv*32 + qd*8);
  aq[1] = *(const bf16x8*)(Qb + ln*256 + (wv+4)*32 + qd*8);

  float se[2][4], sb[2][4];
  #pragma unroll
  for (int hi=0;hi<2;hi++)
    #pragma unroll
    for (int r=0;r<4;r++){ se[hi][r]=0.0f; sb[hi][r]=0.0f; }

  f32x4 oacc[2][2];
  oacc[0][0]=z4; oacc[0][1]=z4; oacc[1][0]=z4; oacc[1][1]=z4;

  uint4 KR[4]; uint2 VR[8]; f32x4 ER;
  // prefetch kt=0
  #pragma unroll
  for (int i=0;i<4;i++)
    KR[i] = *(const uint4*)(Kb + (size_t)(i*8 + srow)*256 + scol);
  #pragma unroll
  for (int j=0;j<8;j++)
    VR[j] = *(const uint2*)(Vtb + (size_t)(vrow + 32*j)*1024 + vcol);
  ER = *(const f32x4*)(ebtab + (size_t)(31 - qh_img)*512 + erow);

  // ---- pass 1: exp once -> both denominators + unnormalized PV ----
  for (int kt=0; kt<32; kt++){
    __syncthreads();
    #pragma unroll
    for (int i=0;i<4;i++) *(uint4*)&Ks[(i*8 + srow)*264 + scol] = KR[i];
    #pragma unroll
    for (int j=0;j<8;j++) *(uint2*)&Vt[(vrow + 32*j)*44 + vcol] = VR[j];
    *(f32x4*)&ebs[erep*532 + erow] = ER;
    *(f32x4*)&ebs[(erep+2)*532 + erow] = ER;
    __syncthreads();
    if (kt < 31){
      #pragma unroll
      for (int i=0;i<4;i++)
        KR[i] = *(const uint4*)(Kb + (size_t)((kt+1)*32 + i*8 + srow)*256 + scol);
      #pragma unroll
      for (int j=0;j<8;j++)
        VR[j] = *(const uint2*)(Vtb + (size_t)(vrow + 32*j)*1024 + (kt+1)*32 + vcol);
      ER = *(const f32x4*)(ebtab + (size_t)(kt + 1 - qh_img + 31)*512 + erow);
    }

    #pragma unroll
    for (int hi=0;hi<2;hi++){
      const int h = wv + hi*4;
      #pragma unroll
      for (int kh=0;kh<2;kh++){
        bf16x8 bk = *(const bf16x8*)&Ks[(kh*16+ln)*264 + h*32 + qd*8];
        f32x4 sc = MFMA16(aq[hi], bk, z4);
        const int kw = kh*16 + ln;
        #pragma unroll
        for (int r=0;r<4;r++){
          float e  = exp2f(sc[r]);                 // Q pre-scaled by log2e/sqrt(dk)
          float eb = e * ebs[qd*532 + h*64 + (kw - (qw0 + qd*4 + r)) + 31];
          se[hi][r] += e;
          sb[hi][r] += eb;
          Ps[wv][(qd*4+r)*40 + kh*16 + ln] = (bf16_t)eb;   // unnormalized
        }
      }
      asm volatile("s_waitcnt lgkmcnt(0)" ::: "memory");
      bf16x8 ap = *(const bf16x8*)&Ps[wv][ln*40 + qd*8];
      #pragma unroll
      for (int nh=0;nh<2;nh++){
        const int n = h*32 + nh*16 + ln;
        bf16x4 vlo = *(const bf16x4*)&Vt[n*44 + qd*8];
        bf16x4 vhi = *(const bf16x4*)&Vt[n*44 + qd*8 + 4];
        bf16x8 bv  = __builtin_shufflevector(vlo, vhi, 0,1,2,3,4,5,6,7);
        oacc[hi][nh] = MFMA16(ap, bv, oacc[hi][nh]);
      }
    }
  }

  // reduce denominators across the 16 column-lanes (same qd group)
  float inv_se[2][4], inv_sb[2][4];
  #pragma unroll
  for (int hi=0;hi<2;hi++)
    #pragma unroll
    for (int r=0;r<4;r++){
      float a = se[hi][r], c = sb[hi][r];
      #pragma unroll
      for (int m=1;m<16;m<<=1){ a += __shfl_xor(a, m, 16); c += __shfl_xor(c, m, 16); }
      inv_se[hi][r] = 1.0f / a;
      inv_sb[hi][r] = 1.0f / c;
    }

  // ---- pass 2: plain probs -> attn_w (mean over heads) ----
  #pragma unroll
  for (int i=0;i<4;i++)
    KR[i] = *(const uint4*)(Kb + (size_t)(i*8 + srow)*256 + scol);

  for (int kt=0; kt<32; kt++){
    __syncthreads();   // also guards uvt union (Vt reads done / awp reads of prev iter done)
    #pragma unroll
    for (int i=0;i<4;i++) *(uint4*)&Ks[(i*8 + srow)*264 + scol] = KR[i];
    __syncthreads();
    if (kt < 31){
      #pragma unroll
      for (int i=0;i<4;i++)
        KR[i] = *(const uint4*)(Kb + (size_t)((kt+1)*32 + i*8 + srow)*256 + scol);
    }

    float paw[2][4];
    #pragma unroll
    for (int hi=0;hi<2;hi++){
      const int h = wv + hi*4;
      #pragma unroll
      for (int kh=0;kh<2;kh++){
        bf16x8 bk = *(const bf16x8*)&Ks[(kh*16+ln)*264 + h*32 + qd*8];
        f32x4 sc = MFMA16(aq[hi], bk, z4);
        #pragma unroll
        for (int r=0;r<4;r++){
          float p = exp2f(sc[r]) * inv_se[hi][r];
          if (hi==0) paw[kh][r]  = p;
          else       paw[kh][r] += p;
        }
      }
    }
    #pragma unroll
    for (int kh=0;kh<2;kh++)
      #pragma unroll
      for (int r=0;r<4;r++)
        awp[wv*528 + (qd*4+r)*33 + kh*16 + ln] = paw[kh][r];
    __syncthreads();
    { int row = t>>4, c = (t&15)*2;
      float s0=0.0f, s1=0.0f;
      #pragma unroll
      for (int w=0;w<4;w++){
        s0 += awp[w*528 + row*33 + c];
        s1 += awp[w*528 + row*33 + c + 1];
      }
      float2 o; o.x = s0*0.125f; o.y = s1*0.125f;
      *(float2*)(AW + (size_t)(b*1024 + qt*16 + row)*1024 + kt*32 + c) = o;
    }
  }

  // ---- ctx out (normalize by biased denominator) ----
  #pragma unroll
  for (int hi=0;hi<2;hi++){
    const int h = wv + hi*4;
    #pragma unroll
    for (int nh=0;nh<2;nh++)
      #pragma unroll
      for (int r=0;r<4;r++)
        ctx[(size_t)(b*1024 + qt*16 + qd*4 + r)*256 + h*32 + nh*16 + ln]
            = f2bf(oacc[hi][nh][r] * inv_sb[hi][r]);
  }
}

// ---------------- K3: out = ctx@Wo^T + bo ; y = LN(out + x). f32 out. ---------------------
__global__ __launch_bounds__(256) void k_outln(
    const u16* __restrict__ CX, const float* __restrict__ Wo,
    const float* __restrict__ bo, const float* __restrict__ xs,
    const float* __restrict__ lgm, const float* __restrict__ lbt,
    float* __restrict__ Out)
{
  __shared__ bf16_t Cts[32*40];
  __shared__ bf16_t Wsh[256*40];
  __shared__ float  Ys[32*260];
  __shared__ float  parts[2][32][2];
  const int t = threadIdx.x;
  const int wv = t>>6, ln = t&15, qd = (t&63)>>4;
  const int wm = wv & 1, wn = wv >> 1;
  const int m0 = blockIdx.x * 32;

  f32x4 z4 = {0.0f,0.0f,0.0f,0.0f};
  f32x4 acc[8];
  #pragma unroll
  for (int i=0;i<8;i++) acc[i] = z4;

  uint2 CR; f32x4 WR[8];
  CR = *(const uint2*)(CX + (size_t)(m0 + (t>>3))*256 + (t&7)*4);
  #pragma unroll
  for (int j=0;j<8;j++)
    WR[j] = *(const f32x4*)(Wo + (size_t)((t>>3)+32*j)*256 + (t&7)*4);

  for (int kt=0; kt<8; kt++){
    __syncthreads();
    { int m = t>>3, k0 = (t&7)*4;
      *(uint2*)&Cts[m*40 + k0] = CR;
    }
    #pragma unroll
    for (int j=0;j<8;j++){
      int n = (t>>3) + 32*j, k0 = (t&7)*4;
      uint2 pk; pk.x = pack2(WR[j][0], WR[j][1]); pk.y = pack2(WR[j][2], WR[j][3]);
      *(uint2*)&Wsh[n*40 + k0] = pk;
    }
    __syncthreads();
    if (kt < 7){
      CR = *(const uint2*)(CX + (size_t)(m0 + (t>>3))*256 + (kt+1)*32 + (t&7)*4);
      #pragma unroll
      for (int j=0;j<8;j++)
        WR[j] = *(const f32x4*)(Wo + (size_t)((t>>3)+32*j)*256 + (kt+1)*32 + (t&7)*4);
    }
    bf16x8 a = *(const bf16x8*)&Cts[(wm*16+ln)*40 + qd*8];
    #pragma unroll
    for (int ni=0;ni<8;ni++){
      bf16x8 bb = *(const bf16x8*)&Wsh[(wn*128 + ni*16 + ln)*40 + qd*8];
      acc[ni] = MFMA16(a, bb, acc[ni]);
    }
  }

  float psum[4]={0,0,0,0}, psq[4]={0,0,0,0};
  #pragma unroll
  for (int ni=0;ni<8;ni++){
    const int col = wn*128 + ni*16 + ln;
    const float bias = bo[col];
    #pragma unroll
    for (int r=0;r<4;r++){
      const int row = wm*16 + qd*4 + r;
      float y = acc[ni][r] + bias + xs[(size_t)(m0+row)*256 + col];
      acc[ni][r] = y;
      psum[r] += y; psq[r] += y*y;
    }
  }
  #pragma unroll
  for (int r=0;r<4;r++){
    float a1 = psum[r], a2 = psq[r];
    #pragma unroll
    for (int m=1;m<16;m<<=1){ a1 += __shfl_xor(a1,m,16); a2 += __shfl_xor(a2,m,16); }
    if (ln == 0){
      parts[wn][wm*16 + qd*4 + r][0] = a1;
      parts[wn][wm*16 + qd*4 + r][1] = a2;
    }
  }
  __syncthreads();
  #pragma unroll
  for (int r=0;r<4;r++){
    const int row = wm*16 + qd*4 + r;
    float mu  = (parts[0][row][0] + parts[1][row][0]) * 0.00390625f;
    float var = (parts[0][row][1] + parts[1][row][1]) * 0.00390625f - mu*mu;
    float rs = rsqrtf(var + 1e-5f);
    #pragma unroll
    for (int ni=0;ni<8;ni++){
      const int col = wn*128 + ni*16 + ln;
      Ys[row*260 + col] = (acc[ni][r] - mu)*rs*lgm[col] + lbt[col];
    }
  }
  __syncthreads();
  { int row = t>>3, c0 = (t&7)*32;
    float* op = Out + (size_t)(m0+row)*256 + c0;
    #pragma unroll
    for (int i=0;i<8;i++)
      *(f32x4*)(op + 4*i) = *(const f32x4*)&Ys[row*260 + c0 + 4*i];
  }
}

// -----------------------------------------------------------------------------------------
extern "C" void kernel_launch(void* const* d_in, const int* in_sizes, int n_in,
                              void* d_out, int out_size, void* d_ws, size_t ws_size,
                              hipStream_t stream)
{
  const float* x   = (const float*)d_in[0];
  const float* wq  = (const float*)d_in[1];
  const float* bq  = (const float*)d_in[2];
  const float* wk  = (const float*)d_in[3];
  const float* bk  = (const float*)d_in[4];
  const float* wv_ = (const float*)d_in[5];
  const float* bv  = (const float*)d_in[6];
  const float* wo  = (const float*)d_in[7];
  const float* bo  = (const float*)d_in[8];
  const float* lng = (const float*)d_in[9];
  const float* lnb = (const float*)d_in[10];
  const float* dib = (const float*)d_in[11];
  const float* drb = (const float*)d_in[12];

  // ws: ebtab 128K | CX bf16 4MB | Vt bf16 4MB = 8.5 MB.
  // d_out f32: y [0, 8MB) ; attn_w [8MB, 41.5MB).
  //   Q bf16 at y bytes [0,4M), K bf16 at y bytes [4M,8M) -> dead before k_outln writes y.
  char*  ws    = (char*)d_ws;
  float* ebtab = (float*)ws;
  u16*   CX    = (u16*)(ws + 131072);
  u16*   Vt    = (u16*)(ws + 131072 + 4194304);
  float* y     = (float*)d_out;
  float* aw    = y + 2097152;
  u16*   Q     = (u16*)y;
  u16*   K     = (u16*)((char*)y + 4194304);

  const float qscale = 0.25503486f;   // log2(e)/sqrt(32) folded into Q

  k_bias_setup<<<16, 256, 0, stream>>>(dib, drb, ebtab);
  k_proj3<<<dim3(256, 3), 256, 0, stream>>>(x, wq, bq, wk, bk, wv_, bv, Q, K, Vt, qscale);
  k_attn_fused<<<dim3(64, 8), 256, 0, stream>>>(Q, K, Vt, ebtab, CX, aw);
  k_outln<<<256, 256, 0, stream>>>(CX, wo, bo, x, lng, lnb, y);  // overwrites Q,K (dead)
}

// Round 2
// 284.847 us; speedup vs baseline: 1.1202x; 1.1202x over previous
//
#include <hip/hip_runtime.h>
#include <stdint.h>

typedef uint16_t u16;
typedef uint32_t u32;
typedef __bf16 bf16_t;
typedef __bf16 bf16x8 __attribute__((ext_vector_type(8)));
typedef __bf16 bf16x4 __attribute__((ext_vector_type(4)));
typedef float  f32x4  __attribute__((ext_vector_type(4)));

#define MFMA16(a,b,c) __builtin_amdgcn_mfma_f32_16x16x32_bf16(a,b,c,0,0,0)

static __device__ __forceinline__ u16 f2bf(float f){
  union { bf16_t b; u16 u; } cv; cv.b = (bf16_t)f; return cv.u;
}
static __device__ __forceinline__ u32 pack2(float a, float b){
  return (u32)f2bf(a) | ((u32)f2bf(b) << 16);
}

// ---------------- K0: exp(bias) table [dh+31][h][dw+31] (63*512 f32) ----------------------
__global__ __launch_bounds__(256) void k_bias_setup(
    const float* __restrict__ dist_bias, const float* __restrict__ dir_bias,
    float* __restrict__ ebtab)
{
  int tid = blockIdx.x*256 + threadIdx.x;
  if (tid >= 63*63) return;
  int dhi = tid / 63, dwi = tid % 63;
  int dh = dhi - 31, dw = dwi - 31;
  int r2 = dh*dh + dw*dw;
  int dist = (int)sqrtf((float)r2);
  if (dist > 59) dist = 59;
  int dir;
  if (dh==0 && dw==0)      dir = 0;
  else if (dh==0)          dir = (dw>0) ? 8  : 0;
  else if (dw==0)          dir = (dh>0) ? 12 : 4;
  else if (dh==dw)         dir = (dh>0) ? 10 : 2;
  else if (dh==-dw)        dir = (dh>0) ? 14 : 6;
  else {
    float ang = atan2f((float)dh, (float)dw) + 3.14159265358979323846f;
    int k = (int)floorf(ang * 2.5464790894703254f);
    dir = k & 15;
  }
  for (int h=0; h<8; h++){
    ebtab[dhi*512 + h*64 + dwi] = expf(dist_bias[dist*8+h] + dir_bias[dir*8+h]);
  }
}

// ---------------- K1: fused Q/K/V projection. blockIdx.y selects matrix. ------------------
// C[8192,256] = X @ W^T + b (f32 in, bf16 MFMA, bf16 out), reg-prefetch double-buffered.
// 3 blocks/CU (grid 768) -> declare 3 waves/EU so prefetch regs don't spill (~170 VGPR cap).
__global__ __launch_bounds__(256, 3) void k_proj3(
    const float* __restrict__ X,
    const float* __restrict__ Wq, const float* __restrict__ Bq,
    const float* __restrict__ Wk, const float* __restrict__ Bk,
    const float* __restrict__ Wv, const float* __restrict__ Bvv,
    u16* __restrict__ Qo, u16* __restrict__ Ko, u16* __restrict__ Vo,
    float qscale)
{
  const float* W; const float* Bv; u16* Out; float scale; int vt_mode;
  if (blockIdx.y == 0)      { W = Wq; Bv = Bq;  Out = Qo; scale = qscale; vt_mode = 0; }
  else if (blockIdx.y == 1) { W = Wk; Bv = Bk;  Out = Ko; scale = 1.0f;   vt_mode = 0; }
  else                      { W = Wv; Bv = Bvv; Out = Vo; scale = 1.0f;   vt_mode = 1; }

  __shared__ bf16_t Xs[32*40];
  __shared__ bf16_t Wsh[256*40];
  __shared__ float  Cs[32*260];
  const int t = threadIdx.x;
  const int wv = t>>6, ln = t&15, qd = (t&63)>>4;
  const int wm = wv & 1, wn = wv >> 1;
  const int m0 = blockIdx.x * 32;

  f32x4 z4 = {0.0f,0.0f,0.0f,0.0f};
  f32x4 acc[8];
  #pragma unroll
  for (int i=0;i<8;i++) acc[i] = z4;

  f32x4 XR; f32x4 WR[8];
  XR = *(const f32x4*)(X + (size_t)(m0 + (t>>3))*256 + (t&7)*4);
  #pragma unroll
  for (int j=0;j<8;j++)
    WR[j] = *(const f32x4*)(W + (size_t)((t>>3)+32*j)*256 + (t&7)*4);

  for (int kt=0; kt<8; kt++){
    __syncthreads();
    { int m = t>>3, k0 = (t&7)*4;
      uint2 pk; pk.x = pack2(XR[0], XR[1]); pk.y = pack2(XR[2], XR[3]);
      *(uint2*)&Xs[m*40 + k0] = pk;
    }
    #pragma unroll
    for (int j=0;j<8;j++){
      int n = (t>>3) + 32*j, k0 = (t&7)*4;
      uint2 pk; pk.x = pack2(WR[j][0], WR[j][1]); pk.y = pack2(WR[j][2], WR[j][3]);
      *(uint2*)&Wsh[n*40 + k0] = pk;
    }
    __syncthreads();
    if (kt < 7){
      XR = *(const f32x4*)(X + (size_t)(m0 + (t>>3))*256 + (kt+1)*32 + (t&7)*4);
      #pragma unroll
      for (int j=0;j<8;j++)
        WR[j] = *(const f32x4*)(W + (size_t)((t>>3)+32*j)*256 + (kt+1)*32 + (t&7)*4);
    }
    bf16x8 a = *(const bf16x8*)&Xs[(wm*16+ln)*40 + qd*8];
    #pragma unroll
    for (int ni=0;ni<8;ni++){
      bf16x8 bb = *(const bf16x8*)&Wsh[(wn*128 + ni*16 + ln)*40 + qd*8];
      acc[ni] = MFMA16(a, bb, acc[ni]);
    }
  }
  __syncthreads();
  #pragma unroll
  for (int ni=0;ni<8;ni++){
    const int col = wn*128 + ni*16 + ln;
    const float bias = Bv[col];
    #pragma unroll
    for (int r=0;r<4;r++){
      Cs[(wm*16 + qd*4 + r)*260 + col] = (acc[ni][r] + bias) * scale;
    }
  }
  __syncthreads();
  if (!vt_mode){
    int row = t>>3, c0 = (t&7)*32;
    u16* op = Out + (size_t)(m0+row)*256 + c0;
    #pragma unroll
    for (int i=0;i<4;i++){
      f32x4 v0 = *(const f32x4*)&Cs[row*260 + c0 + i*8];
      f32x4 v1 = *(const f32x4*)&Cs[row*260 + c0 + i*8 + 4];
      union { u16 h[8]; uint4 v; } pk;
      #pragma unroll
      for (int e=0;e<4;e++){ pk.h[e] = f2bf(v0[e]); pk.h[4+e] = f2bf(v1[e]); }
      *(uint4*)(op + i*8) = pk.v;
    }
  } else {
    const int n = t;
    const int b = m0 >> 10, s0 = m0 & 1023;
    u16* op = Out + (size_t)(b*256 + n)*1024 + s0;
    #pragma unroll
    for (int i=0;i<4;i++){
      union { u16 h[8]; uint4 v; } pk;
      #pragma unroll
      for (int e=0;e<8;e++) pk.h[e] = f2bf(Cs[(i*8+e)*260 + n]);
      *(uint4*)(op + i*8) = pk.v;
    }
  }
}

// ---------------- K2: fused attention: ctx (biased softmax @ V) + attn_w (plain) ----------
// Pass 1: unnormalized-PV with both denominators. Pass 2: plain probs -> attn_w.
// Reg-prefetch double-buffered staging; conflict-free Ks stage map; 4-replica ebs.
// Occupancy is LDS/grid-limited at 2 blocks/CU (= 2 waves/EU) -> declare it so the
// allocator gets a 256-VGPR budget and the prefetch buffers (KR/VR/ER, 36 VGPRs) do
// NOT spill to scratch (round-1 failure: VGPR capped at 72, +18MB scratch WRITE).
__global__ __launch_bounds__(256, 2) void k_attn_fused(
    const u16* __restrict__ Qg, const u16* __restrict__ Kg,
    const u16* __restrict__ Vtg, const float* __restrict__ ebtab,
    u16* __restrict__ ctx, float* __restrict__ AW)
{
  __shared__ bf16_t Ks[32*264];            // 16896 B
  __shared__ __align__(16) char uvt[22528];// pass1: Vt bf16[256*44]; pass2: awp f32[4*528]
  __shared__ bf16_t Ps[4][16*40];          // 5120 B
  __shared__ float  ebs[4*532];            // 8512 B: 4 replicas, stride 532 (conflict-free reads)
  bf16_t* Vt  = (bf16_t*)uvt;
  float*  awp = (float*)uvt;

  const int t  = threadIdx.x;
  const int wv = t >> 6;
  const int ln = t & 15;
  const int qd = (t & 63) >> 4;
  const int b  = blockIdx.y;
  const int qt = blockIdx.x;
  const int qh_img = qt >> 1;
  const int qw0 = (qt & 1) * 16;

  const u16* Qb  = Qg  + (size_t)(b*1024 + qt*16) * 256;
  const u16* Kb  = Kg  + (size_t)b * 1024 * 256;
  const u16* Vtb = Vtg + (size_t)b * 256 * 1024;

  // staging coordinates
  const int srow = t >> 5;          // K stage: base row 0..7
  const int scol = (t & 31) * 8;    // K stage: col in u16 (16B chunks)
  const int vrow = t >> 3;          // Vt stage
  const int vcol = (t & 7) * 4;
  const int erow = (t & 127) * 4;   // ebs stage (dwords)
  const int erep = t >> 7;

  f32x4 z4 = {0.0f,0.0f,0.0f,0.0f};

  bf16x8 aq[2];
  aq[0] = *(const bf16x8*)(Qb + ln*256 + wv*32 + qd*8);
  aq[1] = *(const bf16x8*)(Qb + ln*256 + (wv+4)*32 + qd*8);

  float se[2][4], sb[2][4];
  #pragma unroll
  for (int hi=0;hi<2;hi++)
    #pragma unroll
    for (int r=0;r<4;r++){ se[hi][r]=0.0f; sb[hi][r]=0.0f; }

  f32x4 oacc[2][2];
  oacc[0][0]=z4; oacc[0][1]=z4; oacc[1][0]=z4; oacc[1][1]=z4;

  uint4 KR[4]; uint2 VR[8]; f32x4 ER;
  // prefetch kt=0
  #pragma unroll
  for (int i=0;i<4;i++)
    KR[i] = *(const uint4*)(Kb + (size_t)(i*8 + srow)*256 + scol);
  #pragma unroll
  for (int j=0;j<8;j++)
    VR[j] = *(const uint2*)(Vtb + (size_t)(vrow + 32*j)*1024 + vcol);
  ER = *(const f32x4*)(ebtab + (size_t)(31 - qh_img)*512 + erow);

  // ---- pass 1: exp once -> both denominators + unnormalized PV ----
  for (int kt=0; kt<32; kt++){
    __syncthreads();
    #pragma unroll
    for (int i=0;i<4;i++) *(uint4*)&Ks[(i*8 + srow)*264 + scol] = KR[i];
    #pragma unroll
    for (int j=0;j<8;j++) *(uint2*)&Vt[(vrow + 32*j)*44 + vcol] = VR[j];
    *(f32x4*)&ebs[erep*532 + erow] = ER;
    *(f32x4*)&ebs[(erep+2)*532 + erow] = ER;
    __syncthreads();
    if (kt < 31){
      #pragma unroll
      for (int i=0;i<4;i++)
        KR[i] = *(const uint4*)(Kb + (size_t)((kt+1)*32 + i*8 + srow)*256 + scol);
      #pragma unroll
      for (int j=0;j<8;j++)
        VR[j] = *(const uint2*)(Vtb + (size_t)(vrow + 32*j)*1024 + (kt+1)*32 + vcol);
      ER = *(const f32x4*)(ebtab + (size_t)(kt + 1 - qh_img + 31)*512 + erow);
    }

    #pragma unroll
    for (int hi=0;hi<2;hi++){
      const int h = wv + hi*4;
      #pragma unroll
      for (int kh=0;kh<2;kh++){
        bf16x8 bk = *(const bf16x8*)&Ks[(kh*16+ln)*264 + h*32 + qd*8];
        f32x4 sc = MFMA16(aq[hi], bk, z4);
        const int kw = kh*16 + ln;
        #pragma unroll
        for (int r=0;r<4;r++){
          float e  = exp2f(sc[r]);                 // Q pre-scaled by log2e/sqrt(dk)
          float eb = e * ebs[qd*532 + h*64 + (kw - (qw0 + qd*4 + r)) + 31];
          se[hi][r] += e;
          sb[hi][r] += eb;
          Ps[wv][(qd*4+r)*40 + kh*16 + ln] = (bf16_t)eb;   // unnormalized
        }
      }
      asm volatile("s_waitcnt lgkmcnt(0)" ::: "memory");
      bf16x8 ap = *(const bf16x8*)&Ps[wv][ln*40 + qd*8];
      #pragma unroll
      for (int nh=0;nh<2;nh++){
        const int n = h*32 + nh*16 + ln;
        bf16x4 vlo = *(const bf16x4*)&Vt[n*44 + qd*8];
        bf16x4 vhi = *(const bf16x4*)&Vt[n*44 + qd*8 + 4];
        bf16x8 bv  = __builtin_shufflevector(vlo, vhi, 0,1,2,3,4,5,6,7);
        oacc[hi][nh] = MFMA16(ap, bv, oacc[hi][nh]);
      }
    }
  }

  // prefetch pass-2 kt=0 first so it overlaps the shuffle-reductions below
  #pragma unroll
  for (int i=0;i<4;i++)
    KR[i] = *(const uint4*)(Kb + (size_t)(i*8 + srow)*256 + scol);

  // reduce denominators across the 16 column-lanes (same qd group)
  float inv_se[2][4], inv_sb[2][4];
  #pragma unroll
  for (int hi=0;hi<2;hi++)
    #pragma unroll
    for (int r=0;r<4;r++){
      float a = se[hi][r], c = sb[hi][r];
      #pragma unroll
      for (int m=1;m<16;m<<=1){ a += __shfl_xor(a, m, 16); c += __shfl_xor(c, m, 16); }
      inv_se[hi][r] = 1.0f / a;
      inv_sb[hi][r] = 1.0f / c;
    }

  // ---- pass 2: plain probs -> attn_w (mean over heads) ----
  for (int kt=0; kt<32; kt++){
    __syncthreads();   // also guards uvt union (Vt reads done / awp reads of prev iter done)
    #pragma unroll
    for (int i=0;i<4;i++) *(uint4*)&Ks[(i*8 + srow)*264 + scol] = KR[i];
    __syncthreads();
    if (kt < 31){
      #pragma unroll
      for (int i=0;i<4;i++)
        KR[i] = *(const uint4*)(Kb + (size_t)((kt+1)*32 + i*8 + srow)*256 + scol);
    }

    float paw[2][4];
    #pragma unroll
    for (int hi=0;hi<2;hi++){
      const int h = wv + hi*4;
      #pragma unroll
      for (int kh=0;kh<2;kh++){
        bf16x8 bk = *(const bf16x8*)&Ks[(kh*16+ln)*264 + h*32 + qd*8];
        f32x4 sc = MFMA16(aq[hi], bk, z4);
        #pragma unroll
        for (int r=0;r<4;r++){
          float p = exp2f(sc[r]) * inv_se[hi][r];
          if (hi==0) paw[kh][r]  = p;
          else       paw[kh][r] += p;
        }
      }
    }
    #pragma unroll
    for (int kh=0;kh<2;kh++)
      #pragma unroll
      for (int r=0;r<4;r++)
        awp[wv*528 + (qd*4+r)*33 + kh*16 + ln] = paw[kh][r];
    __syncthreads();
    { int row = t>>4, c = (t&15)*2;
      float s0=0.0f, s1=0.0f;
      #pragma unroll
      for (int w=0;w<4;w++){
        s0 += awp[w*528 + row*33 + c];
        s1 += awp[w*528 + row*33 + c + 1];
      }
      float2 o; o.x = s0*0.125f; o.y = s1*0.125f;
      *(float2*)(AW + (size_t)(b*1024 + qt*16 + row)*1024 + kt*32 + c) = o;
    }
  }

  // ---- ctx out (normalize by biased denominator) ----
  #pragma unroll
  for (int hi=0;hi<2;hi++){
    const int h = wv + hi*4;
    #pragma unroll
    for (int nh=0;nh<2;nh++)
      #pragma unroll
      for (int r=0;r<4;r++)
        ctx[(size_t)(b*1024 + qt*16 + qd*4 + r)*256 + h*32 + nh*16 + ln]
            = f2bf(oacc[hi][nh][r] * inv_sb[hi][r]);
  }
}

// ---------------- K3: out = ctx@Wo^T + bo ; y = LN(out + x). f32 out. ---------------------
// Grid-limited to 1 block/CU -> plenty of VGPR headroom; declare 2 waves/EU cap.
__global__ __launch_bounds__(256, 2) void k_outln(
    const u16* __restrict__ CX, const float* __restrict__ Wo,
    const float* __restrict__ bo, const float* __restrict__ xs,
    const float* __restrict__ lgm, const float* __restrict__ lbt,
    float* __restrict__ Out)
{
  __shared__ bf16_t Cts[32*40];
  __shared__ bf16_t Wsh[256*40];
  __shared__ float  Ys[32*260];
  __shared__ float  parts[2][32][2];
  const int t = threadIdx.x;
  const int wv = t>>6, ln = t&15, qd = (t&63)>>4;
  const int wm = wv & 1, wn = wv >> 1;
  const int m0 = blockIdx.x * 32;

  f32x4 z4 = {0.0f,0.0f,0.0f,0.0f};
  f32x4 acc[8];
  #pragma unroll
  for (int i=0;i<8;i++) acc[i] = z4;

  uint2 CR; f32x4 WR[8];
  CR = *(const uint2*)(CX + (size_t)(m0 + (t>>3))*256 + (t&7)*4);
  #pragma unroll
  for (int j=0;j<8;j++)
    WR[j] = *(const f32x4*)(Wo + (size_t)((t>>3)+32*j)*256 + (t&7)*4);

  for (int kt=0; kt<8; kt++){
    __syncthreads();
    { int m = t>>3, k0 = (t&7)*4;
      *(uint2*)&Cts[m*40 + k0] = CR;
    }
    #pragma unroll
    for (int j=0;j<8;j++){
      int n = (t>>3) + 32*j, k0 = (t&7)*4;
      uint2 pk; pk.x = pack2(WR[j][0], WR[j][1]); pk.y = pack2(WR[j][2], WR[j][3]);
      *(uint2*)&Wsh[n*40 + k0] = pk;
    }
    __syncthreads();
    if (kt < 7){
      CR = *(const uint2*)(CX + (size_t)(m0 + (t>>3))*256 + (kt+1)*32 + (t&7)*4);
      #pragma unroll
      for (int j=0;j<8;j++)
        WR[j] = *(const f32x4*)(Wo + (size_t)((t>>3)+32*j)*256 + (kt+1)*32 + (t&7)*4);
    }
    bf16x8 a = *(const bf16x8*)&Cts[(wm*16+ln)*40 + qd*8];
    #pragma unroll
    for (int ni=0;ni<8;ni++){
      bf16x8 bb = *(const bf16x8*)&Wsh[(wn*128 + ni*16 + ln)*40 + qd*8];
      acc[ni] = MFMA16(a, bb, acc[ni]);
    }
  }

  float psum[4]={0,0,0,0}, psq[4]={0,0,0,0};
  #pragma unroll
  for (int ni=0;ni<8;ni++){
    const int col = wn*128 + ni*16 + ln;
    const float bias = bo[col];
    #pragma unroll
    for (int r=0;r<4;r++){
      const int row = wm*16 + qd*4 + r;
      float y = acc[ni][r] + bias + xs[(size_t)(m0+row)*256 + col];
      acc[ni][r] = y;
      psum[r] += y; psq[r] += y*y;
    }
  }
  #pragma unroll
  for (int r=0;r<4;r++){
    float a1 = psum[r], a2 = psq[r];
    #pragma unroll
    for (int m=1;m<16;m<<=1){ a1 += __shfl_xor(a1,m,16); a2 += __shfl_xor(a2,m,16); }
    if (ln == 0){
      parts[wn][wm*16 + qd*4 + r][0] = a1;
      parts[wn][wm*16 + qd*4 + r][1] = a2;
    }
  }
  __syncthreads();
  #pragma unroll
  for (int r=0;r<4;r++){
    const int row = wm*16 + qd*4 + r;
    float mu  = (parts[0][row][0] + parts[1][row][0]) * 0.00390625f;
    float var = (parts[0][row][1] + parts[1][row][1]) * 0.00390625f - mu*mu;
    float rs = rsqrtf(var + 1e-5f);
    #pragma unroll
    for (int ni=0;ni<8;ni++){
      const int col = wn*128 + ni*16 + ln;
      Ys[row*260 + col] = (acc[ni][r] - mu)*rs*lgm[col] + lbt[col];
    }
  }
  __syncthreads();
  { int row = t>>3, c0 = (t&7)*32;
    float* op = Out + (size_t)(m0+row)*256 + c0;
    #pragma unroll
    for (int i=0;i<8;i++)
      *(f32x4*)(op + 4*i) = *(const f32x4*)&Ys[row*260 + c0 + 4*i];
  }
}

// -----------------------------------------------------------------------------------------
extern "C" void kernel_launch(void* const* d_in, const int* in_sizes, int n_in,
                              void* d_out, int out_size, void* d_ws, size_t ws_size,
                              hipStream_t stream)
{
  const float* x   = (const float*)d_in[0];
  const float* wq  = (const float*)d_in[1];
  const float* bq  = (const float*)d_in[2];
  const float* wk  = (const float*)d_in[3];
  const float* bk  = (const float*)d_in[4];
  const float* wv_ = (const float*)d_in[5];
  const float* bv  = (const float*)d_in[6];
  const float* wo  = (const float*)d_in[7];
  const float* bo  = (const float*)d_in[8];
  const float* lng = (const float*)d_in[9];
  const float* lnb = (const float*)d_in[10];
  const float* dib = (const float*)d_in[11];
  const float* drb = (const float*)d_in[12];

  // ws: ebtab 128K | CX bf16 4MB | Vt bf16 4MB = 8.5 MB.
  // d_out f32: y [0, 8MB) ; attn_w [8MB, 41.5MB).
  //   Q bf16 at y bytes [0,4M), K bf16 at y bytes [4M,8M) -> dead before k_outln writes y.
  char*  ws    = (char*)d_ws;
  float* ebtab = (float*)ws;
  u16*   CX    = (u16*)(ws + 131072);
  u16*   Vt    = (u16*)(ws + 131072 + 4194304);
  float* y     = (float*)d_out;
  float* aw    = y + 2097152;
  u16*   Q     = (u16*)y;
  u16*   K     = (u16*)((char*)y + 4194304);

  const float qscale = 0.25503486f;   // log2(e)/sqrt(32) folded into Q

  k_bias_setup<<<16, 256, 0, stream>>>(dib, drb, ebtab);
  k_proj3<<<dim3(256, 3), 256, 0, stream>>>(x, wq, bq, wk, bk, wv_, bv, Q, K, Vt, qscale);
  k_attn_fused<<<dim3(64, 8), 256, 0, stream>>>(Q, K, Vt, ebtab, CX, aw);
  k_outln<<<256, 256, 0, stream>>>(CX, wo, bo, x, lng, lnb, y);  // overwrites Q,K (dead)
}

// Round 3
// 256.878 us; speedup vs baseline: 1.2422x; 1.1089x over previous
//
#include <hip/hip_runtime.h>
#include <stdint.h>

typedef uint16_t u16;
typedef uint32_t u32;
typedef __bf16 bf16_t;
typedef __bf16 bf16x8 __attribute__((ext_vector_type(8)));
typedef __bf16 bf16x4 __attribute__((ext_vector_type(4)));
typedef float  f32x4  __attribute__((ext_vector_type(4)));

#define MFMA16(a,b,c) __builtin_amdgcn_mfma_f32_16x16x32_bf16(a,b,c,0,0,0)

static __device__ __forceinline__ u16 f2bf(float f){
  union { bf16_t b; u16 u; } cv; cv.b = (bf16_t)f; return cv.u;
}
static __device__ __forceinline__ u32 pack2(float a, float b){
  return (u32)f2bf(a) | ((u32)f2bf(b) << 16);
}

// ---------------- K0: exp(bias) table [dh+31][h][dw+31] (63*512 f32) ----------------------
__global__ __launch_bounds__(256) void k_bias_setup(
    const float* __restrict__ dist_bias, const float* __restrict__ dir_bias,
    float* __restrict__ ebtab)
{
  int tid = blockIdx.x*256 + threadIdx.x;
  if (tid >= 63*63) return;
  int dhi = tid / 63, dwi = tid % 63;
  int dh = dhi - 31, dw = dwi - 31;
  int r2 = dh*dh + dw*dw;
  int dist = (int)sqrtf((float)r2);
  if (dist > 59) dist = 59;
  int dir;
  if (dh==0 && dw==0)      dir = 0;
  else if (dh==0)          dir = (dw>0) ? 8  : 0;
  else if (dw==0)          dir = (dh>0) ? 12 : 4;
  else if (dh==dw)         dir = (dh>0) ? 10 : 2;
  else if (dh==-dw)        dir = (dh>0) ? 14 : 6;
  else {
    float ang = atan2f((float)dh, (float)dw) + 3.14159265358979323846f;
    int k = (int)floorf(ang * 2.5464790894703254f);
    dir = k & 15;
  }
  for (int h=0; h<8; h++){
    ebtab[dhi*512 + h*64 + dwi] = expf(dist_bias[dist*8+h] + dir_bias[dir*8+h]);
  }
}

// ---------------- K1: fused Q/K/V projection. blockIdx.y selects matrix. ------------------
// C[8192,256] = X @ W^T + b (f32 in, bf16 MFMA, bf16 out), reg-prefetch double-buffered.
// LDS 56KB -> 2 blocks/CU max. amdgpu_waves_per_eu(2,2) pins the allocator's occupancy
// target to the REAL occupancy so the 36 prefetch VGPRs don't spill (launch_bounds'
// min-waves arg alone did NOT move the target: VGPR stayed 76 + 65MB scratch writes).
__global__ __attribute__((amdgpu_waves_per_eu(2, 2))) __launch_bounds__(256) void k_proj3(
    const float* __restrict__ X,
    const float* __restrict__ Wq, const float* __restrict__ Bq,
    const float* __restrict__ Wk, const float* __restrict__ Bk,
    const float* __restrict__ Wv, const float* __restrict__ Bvv,
    u16* __restrict__ Qo, u16* __restrict__ Ko, u16* __restrict__ Vo,
    float qscale)
{
  const float* W; const float* Bv; u16* Out; float scale; int vt_mode;
  if (blockIdx.y == 0)      { W = Wq; Bv = Bq;  Out = Qo; scale = qscale; vt_mode = 0; }
  else if (blockIdx.y == 1) { W = Wk; Bv = Bk;  Out = Ko; scale = 1.0f;   vt_mode = 0; }
  else                      { W = Wv; Bv = Bvv; Out = Vo; scale = 1.0f;   vt_mode = 1; }

  __shared__ bf16_t Xs[32*40];
  __shared__ bf16_t Wsh[256*40];
  __shared__ float  Cs[32*260];
  const int t = threadIdx.x;
  const int wv = t>>6, ln = t&15, qd = (t&63)>>4;
  const int wm = wv & 1, wn = wv >> 1;
  const int m0 = blockIdx.x * 32;

  f32x4 z4 = {0.0f,0.0f,0.0f,0.0f};
  f32x4 acc[8];
  #pragma unroll
  for (int i=0;i<8;i++) acc[i] = z4;

  f32x4 XR; f32x4 WR[8];
  XR = *(const f32x4*)(X + (size_t)(m0 + (t>>3))*256 + (t&7)*4);
  #pragma unroll
  for (int j=0;j<8;j++)
    WR[j] = *(const f32x4*)(W + (size_t)((t>>3)+32*j)*256 + (t&7)*4);

  for (int kt=0; kt<8; kt++){
    __syncthreads();
    { int m = t>>3, k0 = (t&7)*4;
      uint2 pk; pk.x = pack2(XR[0], XR[1]); pk.y = pack2(XR[2], XR[3]);
      *(uint2*)&Xs[m*40 + k0] = pk;
    }
    #pragma unroll
    for (int j=0;j<8;j++){
      int n = (t>>3) + 32*j, k0 = (t&7)*4;
      uint2 pk; pk.x = pack2(WR[j][0], WR[j][1]); pk.y = pack2(WR[j][2], WR[j][3]);
      *(uint2*)&Wsh[n*40 + k0] = pk;
    }
    __syncthreads();
    if (kt < 7){
      XR = *(const f32x4*)(X + (size_t)(m0 + (t>>3))*256 + (kt+1)*32 + (t&7)*4);
      #pragma unroll
      for (int j=0;j<8;j++)
        WR[j] = *(const f32x4*)(W + (size_t)((t>>3)+32*j)*256 + (kt+1)*32 + (t&7)*4);
    }
    bf16x8 a = *(const bf16x8*)&Xs[(wm*16+ln)*40 + qd*8];
    #pragma unroll
    for (int ni=0;ni<8;ni++){
      bf16x8 bb = *(const bf16x8*)&Wsh[(wn*128 + ni*16 + ln)*40 + qd*8];
      acc[ni] = MFMA16(a, bb, acc[ni]);
    }
  }
  __syncthreads();
  #pragma unroll
  for (int ni=0;ni<8;ni++){
    const int col = wn*128 + ni*16 + ln;
    const float bias = Bv[col];
    #pragma unroll
    for (int r=0;r<4;r++){
      Cs[(wm*16 + qd*4 + r)*260 + col] = (acc[ni][r] + bias) * scale;
    }
  }
  __syncthreads();
  if (!vt_mode){
    int row = t>>3, c0 = (t&7)*32;
    u16* op = Out + (size_t)(m0+row)*256 + c0;
    #pragma unroll
    for (int i=0;i<4;i++){
      f32x4 v0 = *(const f32x4*)&Cs[row*260 + c0 + i*8];
      f32x4 v1 = *(const f32x4*)&Cs[row*260 + c0 + i*8 + 4];
      union { u16 h[8]; uint4 v; } pk;
      #pragma unroll
      for (int e=0;e<4;e++){ pk.h[e] = f2bf(v0[e]); pk.h[4+e] = f2bf(v1[e]); }
      *(uint4*)(op + i*8) = pk.v;
    }
  } else {
    const int n = t;
    const int b = m0 >> 10, s0 = m0 & 1023;
    u16* op = Out + (size_t)(b*256 + n)*1024 + s0;
    #pragma unroll
    for (int i=0;i<4;i++){
      union { u16 h[8]; uint4 v; } pk;
      #pragma unroll
      for (int e=0;e<8;e++) pk.h[e] = f2bf(Cs[(i*8+e)*260 + n]);
      *(uint4*)(op + i*8) = pk.v;
    }
  }
}

// ---------------- K2: fused attention: ctx (biased softmax @ V) + attn_w (plain) ----------
// Pass 1: unnormalized-PV with both denominators. Pass 2: plain probs -> attn_w.
// Reg-prefetch double-buffered staging; conflict-free Ks stage map; 4-replica ebs.
// LDS 53KB -> 2 blocks/CU. amdgpu_waves_per_eu(2,2) -> 256-VGPR budget so KR/VR/ER
// prefetch stays in registers (r1/r2: allocator targeted ~8 waves/EU, 72-76 VGPRs,
// spilled ~65MB/launch of scratch to HBM).
__global__ __attribute__((amdgpu_waves_per_eu(2, 2))) __launch_bounds__(256) void k_attn_fused(
    const u16* __restrict__ Qg, const u16* __restrict__ Kg,
    const u16* __restrict__ Vtg, const float* __restrict__ ebtab,
    u16* __restrict__ ctx, float* __restrict__ AW)
{
  __shared__ bf16_t Ks[32*264];            // 16896 B
  __shared__ __align__(16) char uvt[22528];// pass1: Vt bf16[256*44]; pass2: awp f32[4*528]
  __shared__ bf16_t Ps[4][16*40];          // 5120 B
  __shared__ float  ebs[4*532];            // 8512 B: 4 replicas, stride 532 (conflict-free reads)
  bf16_t* Vt  = (bf16_t*)uvt;
  float*  awp = (float*)uvt;

  const int t  = threadIdx.x;
  const int wv = t >> 6;
  const int ln = t & 15;
  const int qd = (t & 63) >> 4;
  const int b  = blockIdx.y;
  const int qt = blockIdx.x;
  const int qh_img = qt >> 1;
  const int qw0 = (qt & 1) * 16;

  const u16* Qb  = Qg  + (size_t)(b*1024 + qt*16) * 256;
  const u16* Kb  = Kg  + (size_t)b * 1024 * 256;
  const u16* Vtb = Vtg + (size_t)b * 256 * 1024;

  // staging coordinates
  const int srow = t >> 5;          // K stage: base row 0..7
  const int scol = (t & 31) * 8;    // K stage: col in u16 (16B chunks)
  const int vrow = t >> 3;          // Vt stage
  const int vcol = (t & 7) * 4;
  const int erow = (t & 127) * 4;   // ebs stage (dwords)
  const int erep = t >> 7;

  f32x4 z4 = {0.0f,0.0f,0.0f,0.0f};

  bf16x8 aq[2];
  aq[0] = *(const bf16x8*)(Qb + ln*256 + wv*32 + qd*8);
  aq[1] = *(const bf16x8*)(Qb + ln*256 + (wv+4)*32 + qd*8);

  float se[2][4], sb[2][4];
  #pragma unroll
  for (int hi=0;hi<2;hi++)
    #pragma unroll
    for (int r=0;r<4;r++){ se[hi][r]=0.0f; sb[hi][r]=0.0f; }

  f32x4 oacc[2][2];
  oacc[0][0]=z4; oacc[0][1]=z4; oacc[1][0]=z4; oacc[1][1]=z4;

  uint4 KR[4]; uint2 VR[8]; f32x4 ER;
  // prefetch kt=0
  #pragma unroll
  for (int i=0;i<4;i++)
    KR[i] = *(const uint4*)(Kb + (size_t)(i*8 + srow)*256 + scol);
  #pragma unroll
  for (int j=0;j<8;j++)
    VR[j] = *(const uint2*)(Vtb + (size_t)(vrow + 32*j)*1024 + vcol);
  ER = *(const f32x4*)(ebtab + (size_t)(31 - qh_img)*512 + erow);

  // ---- pass 1: exp once -> both denominators + unnormalized PV ----
  for (int kt=0; kt<32; kt++){
    __syncthreads();
    #pragma unroll
    for (int i=0;i<4;i++) *(uint4*)&Ks[(i*8 + srow)*264 + scol] = KR[i];
    #pragma unroll
    for (int j=0;j<8;j++) *(uint2*)&Vt[(vrow + 32*j)*44 + vcol] = VR[j];
    *(f32x4*)&ebs[erep*532 + erow] = ER;
    *(f32x4*)&ebs[(erep+2)*532 + erow] = ER;
    __syncthreads();
    if (kt < 31){
      #pragma unroll
      for (int i=0;i<4;i++)
        KR[i] = *(const uint4*)(Kb + (size_t)((kt+1)*32 + i*8 + srow)*256 + scol);
      #pragma unroll
      for (int j=0;j<8;j++)
        VR[j] = *(const uint2*)(Vtb + (size_t)(vrow + 32*j)*1024 + (kt+1)*32 + vcol);
      ER = *(const f32x4*)(ebtab + (size_t)(kt + 1 - qh_img + 31)*512 + erow);
    }

    #pragma unroll
    for (int hi=0;hi<2;hi++){
      const int h = wv + hi*4;
      #pragma unroll
      for (int kh=0;kh<2;kh++){
        bf16x8 bk = *(const bf16x8*)&Ks[(kh*16+ln)*264 + h*32 + qd*8];
        f32x4 sc = MFMA16(aq[hi], bk, z4);
        const int kw = kh*16 + ln;
        #pragma unroll
        for (int r=0;r<4;r++){
          float e  = exp2f(sc[r]);                 // Q pre-scaled by log2e/sqrt(dk)
          float eb = e * ebs[qd*532 + h*64 + (kw - (qw0 + qd*4 + r)) + 31];
          se[hi][r] += e;
          sb[hi][r] += eb;
          Ps[wv][(qd*4+r)*40 + kh*16 + ln] = (bf16_t)eb;   // unnormalized
        }
      }
      asm volatile("s_waitcnt lgkmcnt(0)" ::: "memory");
      bf16x8 ap = *(const bf16x8*)&Ps[wv][ln*40 + qd*8];
      #pragma unroll
      for (int nh=0;nh<2;nh++){
        const int n = h*32 + nh*16 + ln;
        bf16x4 vlo = *(const bf16x4*)&Vt[n*44 + qd*8];
        bf16x4 vhi = *(const bf16x4*)&Vt[n*44 + qd*8 + 4];
        bf16x8 bv  = __builtin_shufflevector(vlo, vhi, 0,1,2,3,4,5,6,7);
        oacc[hi][nh] = MFMA16(ap, bv, oacc[hi][nh]);
      }
    }
  }

  // prefetch pass-2 kt=0 first so it overlaps the shuffle-reductions below
  #pragma unroll
  for (int i=0;i<4;i++)
    KR[i] = *(const uint4*)(Kb + (size_t)(i*8 + srow)*256 + scol);

  // reduce denominators across the 16 column-lanes (same qd group)
  float inv_se[2][4], inv_sb[2][4];
  #pragma unroll
  for (int hi=0;hi<2;hi++)
    #pragma unroll
    for (int r=0;r<4;r++){
      float a = se[hi][r], c = sb[hi][r];
      #pragma unroll
      for (int m=1;m<16;m<<=1){ a += __shfl_xor(a, m, 16); c += __shfl_xor(c, m, 16); }
      inv_se[hi][r] = 1.0f / a;
      inv_sb[hi][r] = 1.0f / c;
    }

  // ---- pass 2: plain probs -> attn_w (mean over heads) ----
  for (int kt=0; kt<32; kt++){
    __syncthreads();   // also guards uvt union (Vt reads done / awp reads of prev iter done)
    #pragma unroll
    for (int i=0;i<4;i++) *(uint4*)&Ks[(i*8 + srow)*264 + scol] = KR[i];
    __syncthreads();
    if (kt < 31){
      #pragma unroll
      for (int i=0;i<4;i++)
        KR[i] = *(const uint4*)(Kb + (size_t)((kt+1)*32 + i*8 + srow)*256 + scol);
    }

    float paw[2][4];
    #pragma unroll
    for (int hi=0;hi<2;hi++){
      const int h = wv + hi*4;
      #pragma unroll
      for (int kh=0;kh<2;kh++){
        bf16x8 bk = *(const bf16x8*)&Ks[(kh*16+ln)*264 + h*32 + qd*8];
        f32x4 sc = MFMA16(aq[hi], bk, z4);
        #pragma unroll
        for (int r=0;r<4;r++){
          float p = exp2f(sc[r]) * inv_se[hi][r];
          if (hi==0) paw[kh][r]  = p;
          else       paw[kh][r] += p;
        }
      }
    }
    #pragma unroll
    for (int kh=0;kh<2;kh++)
      #pragma unroll
      for (int r=0;r<4;r++)
        awp[wv*528 + (qd*4+r)*33 + kh*16 + ln] = paw[kh][r];
    __syncthreads();
    { int row = t>>4, c = (t&15)*2;
      float s0=0.0f, s1=0.0f;
      #pragma unroll
      for (int w=0;w<4;w++){
        s0 += awp[w*528 + row*33 + c];
        s1 += awp[w*528 + row*33 + c + 1];
      }
      float2 o; o.x = s0*0.125f; o.y = s1*0.125f;
      *(float2*)(AW + (size_t)(b*1024 + qt*16 + row)*1024 + kt*32 + c) = o;
    }
  }

  // ---- ctx out (normalize by biased denominator) ----
  #pragma unroll
  for (int hi=0;hi<2;hi++){
    const int h = wv + hi*4;
    #pragma unroll
    for (int nh=0;nh<2;nh++)
      #pragma unroll
      for (int r=0;r<4;r++)
        ctx[(size_t)(b*1024 + qt*16 + qd*4 + r)*256 + h*32 + nh*16 + ln]
            = f2bf(oacc[hi][nh][r] * inv_sb[hi][r]);
  }
}

// ---------------- K3: out = ctx@Wo^T + bo ; y = LN(out + x). f32 out. ---------------------
// LDS 56KB -> 2 blocks/CU; same waves_per_eu pin as above.
__global__ __attribute__((amdgpu_waves_per_eu(2, 2))) __launch_bounds__(256) void k_outln(
    const u16* __restrict__ CX, const float* __restrict__ Wo,
    const float* __restrict__ bo, const float* __restrict__ xs,
    const float* __restrict__ lgm, const float* __restrict__ lbt,
    float* __restrict__ Out)
{
  __shared__ bf16_t Cts[32*40];
  __shared__ bf16_t Wsh[256*40];
  __shared__ float  Ys[32*260];
  __shared__ float  parts[2][32][2];
  const int t = threadIdx.x;
  const int wv = t>>6, ln = t&15, qd = (t&63)>>4;
  const int wm = wv & 1, wn = wv >> 1;
  const int m0 = blockIdx.x * 32;

  f32x4 z4 = {0.0f,0.0f,0.0f,0.0f};
  f32x4 acc[8];
  #pragma unroll
  for (int i=0;i<8;i++) acc[i] = z4;

  uint2 CR; f32x4 WR[8];
  CR = *(const uint2*)(CX + (size_t)(m0 + (t>>3))*256 + (t&7)*4);
  #pragma unroll
  for (int j=0;j<8;j++)
    WR[j] = *(const f32x4*)(Wo + (size_t)((t>>3)+32*j)*256 + (t&7)*4);

  for (int kt=0; kt<8; kt++){
    __syncthreads();
    { int m = t>>3, k0 = (t&7)*4;
      *(uint2*)&Cts[m*40 + k0] = CR;
    }
    #pragma unroll
    for (int j=0;j<8;j++){
      int n = (t>>3) + 32*j, k0 = (t&7)*4;
      uint2 pk; pk.x = pack2(WR[j][0], WR[j][1]); pk.y = pack2(WR[j][2], WR[j][3]);
      *(uint2*)&Wsh[n*40 + k0] = pk;
    }
    __syncthreads();
    if (kt < 7){
      CR = *(const uint2*)(CX + (size_t)(m0 + (t>>3))*256 + (kt+1)*32 + (t&7)*4);
      #pragma unroll
      for (int j=0;j<8;j++)
        WR[j] = *(const f32x4*)(Wo + (size_t)((t>>3)+32*j)*256 + (kt+1)*32 + (t&7)*4);
    }
    bf16x8 a = *(const bf16x8*)&Cts[(wm*16+ln)*40 + qd*8];
    #pragma unroll
    for (int ni=0;ni<8;ni++){
      bf16x8 bb = *(const bf16x8*)&Wsh[(wn*128 + ni*16 + ln)*40 + qd*8];
      acc[ni] = MFMA16(a, bb, acc[ni]);
    }
  }

  float psum[4]={0,0,0,0}, psq[4]={0,0,0,0};
  #pragma unroll
  for (int ni=0;ni<8;ni++){
    const int col = wn*128 + ni*16 + ln;
    const float bias = bo[col];
    #pragma unroll
    for (int r=0;r<4;r++){
      const int row = wm*16 + qd*4 + r;
      float y = acc[ni][r] + bias + xs[(size_t)(m0+row)*256 + col];
      acc[ni][r] = y;
      psum[r] += y; psq[r] += y*y;
    }
  }
  #pragma unroll
  for (int r=0;r<4;r++){
    float a1 = psum[r], a2 = psq[r];
    #pragma unroll
    for (int m=1;m<16;m<<=1){ a1 += __shfl_xor(a1,m,16); a2 += __shfl_xor(a2,m,16); }
    if (ln == 0){
      parts[wn][wm*16 + qd*4 + r][0] = a1;
      parts[wn][wm*16 + qd*4 + r][1] = a2;
    }
  }
  __syncthreads();
  #pragma unroll
  for (int r=0;r<4;r++){
    const int row = wm*16 + qd*4 + r;
    float mu  = (parts[0][row][0] + parts[1][row][0]) * 0.00390625f;
    float var = (parts[0][row][1] + parts[1][row][1]) * 0.00390625f - mu*mu;
    float rs = rsqrtf(var + 1e-5f);
    #pragma unroll
    for (int ni=0;ni<8;ni++){
      const int col = wn*128 + ni*16 + ln;
      Ys[row*260 + col] = (acc[ni][r] - mu)*rs*lgm[col] + lbt[col];
    }
  }
  __syncthreads();
  { int row = t>>3, c0 = (t&7)*32;
    float* op = Out + (size_t)(m0+row)*256 + c0;
    #pragma unroll
    for (int i=0;i<8;i++)
      *(f32x4*)(op + 4*i) = *(const f32x4*)&Ys[row*260 + c0 + 4*i];
  }
}

// -----------------------------------------------------------------------------------------
extern "C" void kernel_launch(void* const* d_in, const int* in_sizes, int n_in,
                              void* d_out, int out_size, void* d_ws, size_t ws_size,
                              hipStream_t stream)
{
  const float* x   = (const float*)d_in[0];
  const float* wq  = (const float*)d_in[1];
  const float* bq  = (const float*)d_in[2];
  const float* wk  = (const float*)d_in[3];
  const float* bk  = (const float*)d_in[4];
  const float* wv_ = (const float*)d_in[5];
  const float* bv  = (const float*)d_in[6];
  const float* wo  = (const float*)d_in[7];
  const float* bo  = (const float*)d_in[8];
  const float* lng = (const float*)d_in[9];
  const float* lnb = (const float*)d_in[10];
  const float* dib = (const float*)d_in[11];
  const float* drb = (const float*)d_in[12];

  // ws: ebtab 128K | CX bf16 4MB | Vt bf16 4MB = 8.5 MB.
  // d_out f32: y [0, 8MB) ; attn_w [8MB, 41.5MB).
  //   Q bf16 at y bytes [0,4M), K bf16 at y bytes [4M,8M) -> dead before k_outln writes y.
  char*  ws    = (char*)d_ws;
  float* ebtab = (float*)ws;
  u16*   CX    = (u16*)(ws + 131072);
  u16*   Vt    = (u16*)(ws + 131072 + 4194304);
  float* y     = (float*)d_out;
  float* aw    = y + 2097152;
  u16*   Q     = (u16*)y;
  u16*   K     = (u16*)((char*)y + 4194304);

  const float qscale = 0.25503486f;   // log2(e)/sqrt(32) folded into Q

  k_bias_setup<<<16, 256, 0, stream>>>(dib, drb, ebtab);
  k_proj3<<<dim3(256, 3), 256, 0, stream>>>(x, wq, bq, wk, bk, wv_, bv, Q, K, Vt, qscale);
  k_attn_fused<<<dim3(64, 8), 256, 0, stream>>>(Q, K, Vt, ebtab, CX, aw);
  k_outln<<<256, 256, 0, stream>>>(CX, wo, bo, x, lng, lnb, y);  // overwrites Q,K (dead)
}

// Round 4
// 225.345 us; speedup vs baseline: 1.4160x; 1.1399x over previous
//
#include <hip/hip_runtime.h>
#include <stdint.h>

typedef uint16_t u16;
typedef uint32_t u32;
typedef __bf16 bf16_t;
typedef __bf16 bf16x8 __attribute__((ext_vector_type(8)));
typedef __bf16 bf16x4 __attribute__((ext_vector_type(4)));
typedef float  f32x4  __attribute__((ext_vector_type(4)));

#define MFMA16(a,b,c) __builtin_amdgcn_mfma_f32_16x16x32_bf16(a,b,c,0,0,0)

static __device__ __forceinline__ u16 f2bf(float f){
  union { bf16_t b; u16 u; } cv; cv.b = (bf16_t)f; return cv.u;
}
static __device__ __forceinline__ u32 pack2(float a, float b){
  return (u32)f2bf(a) | ((u32)f2bf(b) << 16);
}

// ---------------- K0: exp(bias) table [dh+31][h][dw+31] (63*512 f32) ----------------------
__global__ __launch_bounds__(256) void k_bias_setup(
    const float* __restrict__ dist_bias, const float* __restrict__ dir_bias,
    float* __restrict__ ebtab)
{
  int tid = blockIdx.x*256 + threadIdx.x;
  if (tid >= 63*63) return;
  int dhi = tid / 63, dwi = tid % 63;
  int dh = dhi - 31, dw = dwi - 31;
  int r2 = dh*dh + dw*dw;
  int dist = (int)sqrtf((float)r2);
  if (dist > 59) dist = 59;
  int dir;
  if (dh==0 && dw==0)      dir = 0;
  else if (dh==0)          dir = (dw>0) ? 8  : 0;
  else if (dw==0)          dir = (dh>0) ? 12 : 4;
  else if (dh==dw)         dir = (dh>0) ? 10 : 2;
  else if (dh==-dw)        dir = (dh>0) ? 14 : 6;
  else {
    float ang = atan2f((float)dh, (float)dw) + 3.14159265358979323846f;
    int k = (int)floorf(ang * 2.5464790894703254f);
    dir = k & 15;
  }
  for (int h=0; h<8; h++){
    ebtab[dhi*512 + h*64 + dwi] = expf(dist_bias[dist*8+h] + dir_bias[dir*8+h]);
  }
}

// ---------------- K1: fused Q/K/V projection. blockIdx.y selects matrix. ------------------
// C[8192,256] = X @ W^T + b (f32 in, bf16 MFMA, bf16 out), reg-prefetch double-buffered.
__global__ __attribute__((amdgpu_waves_per_eu(2, 2))) __launch_bounds__(256) void k_proj3(
    const float* __restrict__ X,
    const float* __restrict__ Wq, const float* __restrict__ Bq,
    const float* __restrict__ Wk, const float* __restrict__ Bk,
    const float* __restrict__ Wv, const float* __restrict__ Bvv,
    u16* __restrict__ Qo, u16* __restrict__ Ko, u16* __restrict__ Vo,
    float qscale)
{
  const float* W; const float* Bv; u16* Out; float scale; int vt_mode;
  if (blockIdx.y == 0)      { W = Wq; Bv = Bq;  Out = Qo; scale = qscale; vt_mode = 0; }
  else if (blockIdx.y == 1) { W = Wk; Bv = Bk;  Out = Ko; scale = 1.0f;   vt_mode = 0; }
  else                      { W = Wv; Bv = Bvv; Out = Vo; scale = 1.0f;   vt_mode = 1; }

  __shared__ bf16_t Xs[32*40];
  __shared__ bf16_t Wsh[256*40];
  __shared__ float  Cs[32*260];
  const int t = threadIdx.x;
  const int wv = t>>6, ln = t&15, qd = (t&63)>>4;
  const int wm = wv & 1, wn = wv >> 1;
  const int m0 = blockIdx.x * 32;

  f32x4 z4 = {0.0f,0.0f,0.0f,0.0f};
  f32x4 acc[8];
  #pragma unroll
  for (int i=0;i<8;i++) acc[i] = z4;

  f32x4 XR; f32x4 WR[8];
  XR = *(const f32x4*)(X + (size_t)(m0 + (t>>3))*256 + (t&7)*4);
  #pragma unroll
  for (int j=0;j<8;j++)
    WR[j] = *(const f32x4*)(W + (size_t)((t>>3)+32*j)*256 + (t&7)*4);

  for (int kt=0; kt<8; kt++){
    __syncthreads();
    { int m = t>>3, k0 = (t&7)*4;
      uint2 pk; pk.x = pack2(XR[0], XR[1]); pk.y = pack2(XR[2], XR[3]);
      *(uint2*)&Xs[m*40 + k0] = pk;
    }
    #pragma unroll
    for (int j=0;j<8;j++){
      int n = (t>>3) + 32*j, k0 = (t&7)*4;
      uint2 pk; pk.x = pack2(WR[j][0], WR[j][1]); pk.y = pack2(WR[j][2], WR[j][3]);
      *(uint2*)&Wsh[n*40 + k0] = pk;
    }
    __syncthreads();
    if (kt < 7){
      XR = *(const f32x4*)(X + (size_t)(m0 + (t>>3))*256 + (kt+1)*32 + (t&7)*4);
      #pragma unroll
      for (int j=0;j<8;j++)
        WR[j] = *(const f32x4*)(W + (size_t)((t>>3)+32*j)*256 + (kt+1)*32 + (t&7)*4);
    }
    bf16x8 a = *(const bf16x8*)&Xs[(wm*16+ln)*40 + qd*8];
    #pragma unroll
    for (int ni=0;ni<8;ni++){
      bf16x8 bb = *(const bf16x8*)&Wsh[(wn*128 + ni*16 + ln)*40 + qd*8];
      acc[ni] = MFMA16(a, bb, acc[ni]);
    }
  }
  __syncthreads();
  #pragma unroll
  for (int ni=0;ni<8;ni++){
    const int col = wn*128 + ni*16 + ln;
    const float bias = Bv[col];
    #pragma unroll
    for (int r=0;r<4;r++){
      Cs[(wm*16 + qd*4 + r)*260 + col] = (acc[ni][r] + bias) * scale;
    }
  }
  __syncthreads();
  if (!vt_mode){
    int row = t>>3, c0 = (t&7)*32;
    u16* op = Out + (size_t)(m0+row)*256 + c0;
    #pragma unroll
    for (int i=0;i<4;i++){
      f32x4 v0 = *(const f32x4*)&Cs[row*260 + c0 + i*8];
      f32x4 v1 = *(const f32x4*)&Cs[row*260 + c0 + i*8 + 4];
      union { u16 h[8]; uint4 v; } pk;
      #pragma unroll
      for (int e=0;e<4;e++){ pk.h[e] = f2bf(v0[e]); pk.h[4+e] = f2bf(v1[e]); }
      *(uint4*)(op + i*8) = pk.v;
    }
  } else {
    const int n = t;
    const int b = m0 >> 10, s0 = m0 & 1023;
    u16* op = Out + (size_t)(b*256 + n)*1024 + s0;
    #pragma unroll
    for (int i=0;i<4;i++){
      union { u16 h[8]; uint4 v; } pk;
      #pragma unroll
      for (int e=0;e<8;e++) pk.h[e] = f2bf(Cs[(i*8+e)*260 + n]);
      *(uint4*)(op + i*8) = pk.v;
    }
  }
}

// ---------------- K2: fused attention: ctx (biased softmax @ V) + attn_w (plain) ----------
// NO LDS STAGING: K/V are L2-resident (1 MB/batch) -> fragments loaded directly
// global->VGPR. Bias row via 2 coalesced loads + bpermute shfl. Pass 1 has ZERO
// barriers. Pass 2: one 512B invTab exchange (1 barrier), then each wave owns a
// disjoint kt-range, recomputes scores for all 8 heads, sums heads in-register ->
// writes AW directly (no LDS reduction, no barriers).
// (r1-r3 lesson: reg-prefetch + LDS staging fought the allocator -> scratch/LDS
// spills; the real fix is removing the staging + barriers altogether.)
__global__ __attribute__((amdgpu_waves_per_eu(2, 2))) __launch_bounds__(256) void k_attn_fused(
    const u16* __restrict__ Qg, const u16* __restrict__ Kg,
    const u16* __restrict__ Vtg, const float* __restrict__ ebtab,
    u16* __restrict__ ctx, float* __restrict__ AW)
{
  __shared__ bf16_t Ps[4][16*40];          // 5120 B, wave-private (lgkm-wait only)
  __shared__ float  invTab[8][16];         // 512 B, one-time exchange

  const int t  = threadIdx.x;
  const int wv = t >> 6;
  const int ln = t & 15;
  const int qd = (t & 63) >> 4;
  const int lane = t & 63;
  const int b  = blockIdx.y;
  const int qt = blockIdx.x;
  const int qh_img = qt >> 1;
  const int qw0 = (qt & 1) * 16;

  const u16* Qb  = Qg  + (size_t)(b*1024 + qt*16) * 256;
  const u16* Kb  = Kg  + (size_t)b * 1024 * 256;
  const u16* Vtb = Vtg + (size_t)b * 256 * 1024;

  f32x4 z4 = {0.0f,0.0f,0.0f,0.0f};

  bf16x8 aq[2];
  aq[0] = *(const bf16x8*)(Qb + ln*256 + wv*32 + qd*8);
  aq[1] = *(const bf16x8*)(Qb + ln*256 + (wv+4)*32 + qd*8);

  float se[2][4], sb[2][4];
  #pragma unroll
  for (int hi=0;hi<2;hi++)
    #pragma unroll
    for (int r=0;r<4;r++){ se[hi][r]=0.0f; sb[hi][r]=0.0f; }

  f32x4 oacc[2][2];
  oacc[0][0]=z4; oacc[0][1]=z4; oacc[1][0]=z4; oacc[1][1]=z4;

  // ---- pass 1: exp once -> both denominators + unnormalized PV. No barriers. ----
  for (int kt=0; kt<32; kt++){
    const int row = kt - qh_img + 31;
    // bias row segments for this wave's two heads: coalesced 256B loads, L2-hot
    float e0 = ebtab[(size_t)row*512 + wv*64 + lane];
    float e1 = ebtab[(size_t)row*512 + (wv+4)*64 + lane];

    #pragma unroll
    for (int hi=0;hi<2;hi++){
      const int h = wv + hi*4;
      #pragma unroll
      for (int kh=0;kh<2;kh++){
        bf16x8 bk = *(const bf16x8*)(Kb + (size_t)(kt*32 + kh*16 + ln)*256 + h*32 + qd*8);
        f32x4 sc = MFMA16(aq[hi], bk, z4);
        #pragma unroll
        for (int r=0;r<4;r++){
          float e  = exp2f(sc[r]);                 // Q pre-scaled by log2e/sqrt(dk)
          int idx = kh*16 + ln - (qw0 + qd*4 + r) + 31;   // dw+31 in [0,62]
          float ebv = __shfl(hi==0 ? e0 : e1, idx);
          float eb = e * ebv;
          se[hi][r] += e;
          sb[hi][r] += eb;
          Ps[wv][(qd*4+r)*40 + kh*16 + ln] = (bf16_t)eb;   // unnormalized
        }
      }
      asm volatile("s_waitcnt lgkmcnt(0)" ::: "memory");
      bf16x8 ap = *(const bf16x8*)&Ps[wv][ln*40 + qd*8];
      #pragma unroll
      for (int nh=0;nh<2;nh++){
        const int n = h*32 + nh*16 + ln;
        bf16x8 bv = *(const bf16x8*)(Vtb + (size_t)n*1024 + kt*32 + qd*8);
        oacc[hi][nh] = MFMA16(ap, bv, oacc[hi][nh]);
      }
    }
  }

  // reduce denominators across the 16 column-lanes (same qd group)
  float inv_se[2][4], inv_sb[2][4];
  #pragma unroll
  for (int hi=0;hi<2;hi++)
    #pragma unroll
    for (int r=0;r<4;r++){
      float a = se[hi][r], c = sb[hi][r];
      #pragma unroll
      for (int m=1;m<16;m<<=1){ a += __shfl_xor(a, m, 16); c += __shfl_xor(c, m, 16); }
      inv_se[hi][r] = 1.0f / a;
      inv_sb[hi][r] = 1.0f / c;
    }

  // ---- one-time exchange of plain-softmax denominators across waves ----
  if (ln == 0){
    #pragma unroll
    for (int r=0;r<4;r++){
      invTab[wv][qd*4+r]   = inv_se[0][r];
      invTab[wv+4][qd*4+r] = inv_se[1][r];
    }
  }
  __syncthreads();
  float invq[8][4];
  #pragma unroll
  for (int h=0;h<8;h++)
    #pragma unroll
    for (int r=0;r<4;r++)
      invq[h][r] = invTab[h][qd*4+r];

  // Q fragments for all 8 heads (L1/L2-hot re-read; constant-indexed after unroll)
  bf16x8 aqAll[8];
  #pragma unroll
  for (int h=0;h<8;h++)
    aqAll[h] = *(const bf16x8*)(Qb + ln*256 + h*32 + qd*8);

  // ---- pass 2: plain probs -> attn_w (mean over heads). Wave owns kt-range;
  //      head-sum entirely in-register. No barriers. ----
  for (int kti=0; kti<8; kti++){
    const int kt = wv*8 + kti;
    float aw0[2][4];
    #pragma unroll
    for (int kh=0;kh<2;kh++)
      #pragma unroll
      for (int r=0;r<4;r++) aw0[kh][r] = 0.0f;

    #pragma unroll
    for (int h=0;h<8;h++){
      #pragma unroll
      for (int kh=0;kh<2;kh++){
        bf16x8 bk = *(const bf16x8*)(Kb + (size_t)(kt*32 + kh*16 + ln)*256 + h*32 + qd*8);
        f32x4 sc = MFMA16(aqAll[h], bk, z4);
        #pragma unroll
        for (int r=0;r<4;r++)
          aw0[kh][r] += exp2f(sc[r]) * invq[h][r];
      }
    }
    #pragma unroll
    for (int kh=0;kh<2;kh++)
      #pragma unroll
      for (int r=0;r<4;r++)
        AW[(size_t)(b*1024 + qt*16 + qd*4 + r)*1024 + kt*32 + kh*16 + ln]
            = aw0[kh][r] * 0.125f;
  }

  // ---- ctx out (normalize by biased denominator) ----
  #pragma unroll
  for (int hi=0;hi<2;hi++){
    const int h = wv + hi*4;
    #pragma unroll
    for (int nh=0;nh<2;nh++)
      #pragma unroll
      for (int r=0;r<4;r++)
        ctx[(size_t)(b*1024 + qt*16 + qd*4 + r)*256 + h*32 + nh*16 + ln]
            = f2bf(oacc[hi][nh][r] * inv_sb[hi][r]);
  }
}

// ---------------- K3: out = ctx@Wo^T + bo ; y = LN(out + x). f32 out. ---------------------
__global__ __attribute__((amdgpu_waves_per_eu(2, 2))) __launch_bounds__(256) void k_outln(
    const u16* __restrict__ CX, const float* __restrict__ Wo,
    const float* __restrict__ bo, const float* __restrict__ xs,
    const float* __restrict__ lgm, const float* __restrict__ lbt,
    float* __restrict__ Out)
{
  __shared__ bf16_t Cts[32*40];
  __shared__ bf16_t Wsh[256*40];
  __shared__ float  Ys[32*260];
  __shared__ float  parts[2][32][2];
  const int t = threadIdx.x;
  const int wv = t>>6, ln = t&15, qd = (t&63)>>4;
  const int wm = wv & 1, wn = wv >> 1;
  const int m0 = blockIdx.x * 32;

  f32x4 z4 = {0.0f,0.0f,0.0f,0.0f};
  f32x4 acc[8];
  #pragma unroll
  for (int i=0;i<8;i++) acc[i] = z4;

  uint2 CR; f32x4 WR[8];
  CR = *(const uint2*)(CX + (size_t)(m0 + (t>>3))*256 + (t&7)*4);
  #pragma unroll
  for (int j=0;j<8;j++)
    WR[j] = *(const f32x4*)(Wo + (size_t)((t>>3)+32*j)*256 + (t&7)*4);

  for (int kt=0; kt<8; kt++){
    __syncthreads();
    { int m = t>>3, k0 = (t&7)*4;
      *(uint2*)&Cts[m*40 + k0] = CR;
    }
    #pragma unroll
    for (int j=0;j<8;j++){
      int n = (t>>3) + 32*j, k0 = (t&7)*4;
      uint2 pk; pk.x = pack2(WR[j][0], WR[j][1]); pk.y = pack2(WR[j][2], WR[j][3]);
      *(uint2*)&Wsh[n*40 + k0] = pk;
    }
    __syncthreads();
    if (kt < 7){
      CR = *(const uint2*)(CX + (size_t)(m0 + (t>>3))*256 + (kt+1)*32 + (t&7)*4);
      #pragma unroll
      for (int j=0;j<8;j++)
        WR[j] = *(const f32x4*)(Wo + (size_t)((t>>3)+32*j)*256 + (kt+1)*32 + (t&7)*4);
    }
    bf16x8 a = *(const bf16x8*)&Cts[(wm*16+ln)*40 + qd*8];
    #pragma unroll
    for (int ni=0;ni<8;ni++){
      bf16x8 bb = *(const bf16x8*)&Wsh[(wn*128 + ni*16 + ln)*40 + qd*8];
      acc[ni] = MFMA16(a, bb, acc[ni]);
    }
  }

  float psum[4]={0,0,0,0}, psq[4]={0,0,0,0};
  #pragma unroll
  for (int ni=0;ni<8;ni++){
    const int col = wn*128 + ni*16 + ln;
    const float bias = bo[col];
    #pragma unroll
    for (int r=0;r<4;r++){
      const int row = wm*16 + qd*4 + r;
      float y = acc[ni][r] + bias + xs[(size_t)(m0+row)*256 + col];
      acc[ni][r] = y;
      psum[r] += y; psq[r] += y*y;
    }
  }
  #pragma unroll
  for (int r=0;r<4;r++){
    float a1 = psum[r], a2 = psq[r];
    #pragma unroll
    for (int m=1;m<16;m<<=1){ a1 += __shfl_xor(a1,m,16); a2 += __shfl_xor(a2,m,16); }
    if (ln == 0){
      parts[wn][wm*16 + qd*4 + r][0] = a1;
      parts[wn][wm*16 + qd*4 + r][1] = a2;
    }
  }
  __syncthreads();
  #pragma unroll
  for (int r=0;r<4;r++){
    const int row = wm*16 + qd*4 + r;
    float mu  = (parts[0][row][0] + parts[1][row][0]) * 0.00390625f;
    float var = (parts[0][row][1] + parts[1][row][1]) * 0.00390625f - mu*mu;
    float rs = rsqrtf(var + 1e-5f);
    #pragma unroll
    for (int ni=0;ni<8;ni++){
      const int col = wn*128 + ni*16 + ln;
      Ys[row*260 + col] = (acc[ni][r] - mu)*rs*lgm[col] + lbt[col];
    }
  }
  __syncthreads();
  { int row = t>>3, c0 = (t&7)*32;
    float* op = Out + (size_t)(m0+row)*256 + c0;
    #pragma unroll
    for (int i=0;i<8;i++)
      *(f32x4*)(op + 4*i) = *(const f32x4*)&Ys[row*260 + c0 + 4*i];
  }
}

// -----------------------------------------------------------------------------------------
extern "C" void kernel_launch(void* const* d_in, const int* in_sizes, int n_in,
                              void* d_out, int out_size, void* d_ws, size_t ws_size,
                              hipStream_t stream)
{
  const float* x   = (const float*)d_in[0];
  const float* wq  = (const float*)d_in[1];
  const float* bq  = (const float*)d_in[2];
  const float* wk  = (const float*)d_in[3];
  const float* bk  = (const float*)d_in[4];
  const float* wv_ = (const float*)d_in[5];
  const float* bv  = (const float*)d_in[6];
  const float* wo  = (const float*)d_in[7];
  const float* bo  = (const float*)d_in[8];
  const float* lng = (const float*)d_in[9];
  const float* lnb = (const float*)d_in[10];
  const float* dib = (const float*)d_in[11];
  const float* drb = (const float*)d_in[12];

  // ws: ebtab 128K | CX bf16 4MB | Vt bf16 4MB = 8.5 MB.
  // d_out f32: y [0, 8MB) ; attn_w [8MB, 41.5MB).
  //   Q bf16 at y bytes [0,4M), K bf16 at y bytes [4M,8M) -> dead before k_outln writes y.
  char*  ws    = (char*)d_ws;
  float* ebtab = (float*)ws;
  u16*   CX    = (u16*)(ws + 131072);
  u16*   Vt    = (u16*)(ws + 131072 + 4194304);
  float* y     = (float*)d_out;
  float* aw    = y + 2097152;
  u16*   Q     = (u16*)y;
  u16*   K     = (u16*)((char*)y + 4194304);

  const float qscale = 0.25503486f;   // log2(e)/sqrt(32) folded into Q

  k_bias_setup<<<16, 256, 0, stream>>>(dib, drb, ebtab);
  k_proj3<<<dim3(256, 3), 256, 0, stream>>>(x, wq, bq, wk, bk, wv_, bv, Q, K, Vt, qscale);
  k_attn_fused<<<dim3(64, 8), 256, 0, stream>>>(Q, K, Vt, ebtab, CX, aw);
  k_outln<<<256, 256, 0, stream>>>(CX, wo, bo, x, lng, lnb, y);  // overwrites Q,K (dead)
}

// Round 5
// 219.392 us; speedup vs baseline: 1.4544x; 1.0271x over previous
//
#include <hip/hip_runtime.h>
#include <stdint.h>

typedef uint16_t u16;
typedef uint32_t u32;
typedef __bf16 bf16_t;
typedef __bf16 bf16x8 __attribute__((ext_vector_type(8)));
typedef __bf16 bf16x4 __attribute__((ext_vector_type(4)));
typedef float  f32x4  __attribute__((ext_vector_type(4)));

#define MFMA16(a,b,c) __builtin_amdgcn_mfma_f32_16x16x32_bf16(a,b,c,0,0,0)

static __device__ __forceinline__ u16 f2bf(float f){
  union { bf16_t b; u16 u; } cv; cv.b = (bf16_t)f; return cv.u;
}
static __device__ __forceinline__ u32 pack2(float a, float b){
  return (u32)f2bf(a) | ((u32)f2bf(b) << 16);
}

// ---------------- K0: exp(bias) table [dh+31][h][dw+31] (63*512 f32) ----------------------
__global__ __launch_bounds__(256) void k_bias_setup(
    const float* __restrict__ dist_bias, const float* __restrict__ dir_bias,
    float* __restrict__ ebtab)
{
  int tid = blockIdx.x*256 + threadIdx.x;
  if (tid >= 63*63) return;
  int dhi = tid / 63, dwi = tid % 63;
  int dh = dhi - 31, dw = dwi - 31;
  int r2 = dh*dh + dw*dw;
  int dist = (int)sqrtf((float)r2);
  if (dist > 59) dist = 59;
  int dir;
  if (dh==0 && dw==0)      dir = 0;
  else if (dh==0)          dir = (dw>0) ? 8  : 0;
  else if (dw==0)          dir = (dh>0) ? 12 : 4;
  else if (dh==dw)         dir = (dh>0) ? 10 : 2;
  else if (dh==-dw)        dir = (dh>0) ? 14 : 6;
  else {
    float ang = atan2f((float)dh, (float)dw) + 3.14159265358979323846f;
    int k = (int)floorf(ang * 2.5464790894703254f);
    dir = k & 15;
  }
  for (int h=0; h<8; h++){
    ebtab[dhi*512 + h*64 + dwi] = expf(dist_bias[dist*8+h] + dir_bias[dir*8+h]);
  }
}

// ---------------- K1: fused Q/K/V projection. blockIdx.y selects matrix. ------------------
// C[8192,256] = X @ W^T + b (f32 in, bf16 MFMA, bf16 out), reg-prefetch double-buffered.
// Wsh/Cs lifetimes are disjoint (barrier between) -> union drops LDS 56->35.8KB so all
// 3 blocks/CU are resident in ONE dispatch round (was 2 rounds of 512+256 blocks).
__global__ __attribute__((amdgpu_waves_per_eu(3, 3))) __launch_bounds__(256) void k_proj3(
    const float* __restrict__ X,
    const float* __restrict__ Wq, const float* __restrict__ Bq,
    const float* __restrict__ Wk, const float* __restrict__ Bk,
    const float* __restrict__ Wv, const float* __restrict__ Bvv,
    u16* __restrict__ Qo, u16* __restrict__ Ko, u16* __restrict__ Vo,
    float qscale)
{
  const float* W; const float* Bv; u16* Out; float scale; int vt_mode;
  if (blockIdx.y == 0)      { W = Wq; Bv = Bq;  Out = Qo; scale = qscale; vt_mode = 0; }
  else if (blockIdx.y == 1) { W = Wk; Bv = Bk;  Out = Ko; scale = 1.0f;   vt_mode = 0; }
  else                      { W = Wv; Bv = Bvv; Out = Vo; scale = 1.0f;   vt_mode = 1; }

  __shared__ bf16_t Xs[32*40];
  __shared__ __align__(16) char UU[33280];   // union: Wsh bf16[256*40]=20480B | Cs f32[32*260]=33280B
  bf16_t* Wsh = (bf16_t*)UU;
  float*  Cs  = (float*)UU;
  const int t = threadIdx.x;
  const int wv = t>>6, ln = t&15, qd = (t&63)>>4;
  const int wm = wv & 1, wn = wv >> 1;
  const int m0 = blockIdx.x * 32;

  f32x4 z4 = {0.0f,0.0f,0.0f,0.0f};
  f32x4 acc[8];
  #pragma unroll
  for (int i=0;i<8;i++) acc[i] = z4;

  f32x4 XR; f32x4 WR[8];
  XR = *(const f32x4*)(X + (size_t)(m0 + (t>>3))*256 + (t&7)*4);
  #pragma unroll
  for (int j=0;j<8;j++)
    WR[j] = *(const f32x4*)(W + (size_t)((t>>3)+32*j)*256 + (t&7)*4);

  for (int kt=0; kt<8; kt++){
    __syncthreads();
    { int m = t>>3, k0 = (t&7)*4;
      uint2 pk; pk.x = pack2(XR[0], XR[1]); pk.y = pack2(XR[2], XR[3]);
      *(uint2*)&Xs[m*40 + k0] = pk;
    }
    #pragma unroll
    for (int j=0;j<8;j++){
      int n = (t>>3) + 32*j, k0 = (t&7)*4;
      uint2 pk; pk.x = pack2(WR[j][0], WR[j][1]); pk.y = pack2(WR[j][2], WR[j][3]);
      *(uint2*)&Wsh[n*40 + k0] = pk;
    }
    __syncthreads();
    if (kt < 7){
      XR = *(const f32x4*)(X + (size_t)(m0 + (t>>3))*256 + (kt+1)*32 + (t&7)*4);
      #pragma unroll
      for (int j=0;j<8;j++)
        WR[j] = *(const f32x4*)(W + (size_t)((t>>3)+32*j)*256 + (kt+1)*32 + (t&7)*4);
    }
    bf16x8 a = *(const bf16x8*)&Xs[(wm*16+ln)*40 + qd*8];
    #pragma unroll
    for (int ni=0;ni<8;ni++){
      bf16x8 bb = *(const bf16x8*)&Wsh[(wn*128 + ni*16 + ln)*40 + qd*8];
      acc[ni] = MFMA16(a, bb, acc[ni]);
    }
  }
  __syncthreads();   // Wsh dead after this point; Cs takes over the union
  #pragma unroll
  for (int ni=0;ni<8;ni++){
    const int col = wn*128 + ni*16 + ln;
    const float bias = Bv[col];
    #pragma unroll
    for (int r=0;r<4;r++){
      Cs[(wm*16 + qd*4 + r)*260 + col] = (acc[ni][r] + bias) * scale;
    }
  }
  __syncthreads();
  if (!vt_mode){
    int row = t>>3, c0 = (t&7)*32;
    u16* op = Out + (size_t)(m0+row)*256 + c0;
    #pragma unroll
    for (int i=0;i<4;i++){
      f32x4 v0 = *(const f32x4*)&Cs[row*260 + c0 + i*8];
      f32x4 v1 = *(const f32x4*)&Cs[row*260 + c0 + i*8 + 4];
      union { u16 h[8]; uint4 v; } pk;
      #pragma unroll
      for (int e=0;e<4;e++){ pk.h[e] = f2bf(v0[e]); pk.h[4+e] = f2bf(v1[e]); }
      *(uint4*)(op + i*8) = pk.v;
    }
  } else {
    const int n = t;
    const int b = m0 >> 10, s0 = m0 & 1023;
    u16* op = Out + (size_t)(b*256 + n)*1024 + s0;
    #pragma unroll
    for (int i=0;i<4;i++){
      union { u16 h[8]; uint4 v; } pk;
      #pragma unroll
      for (int e=0;e<8;e++) pk.h[e] = f2bf(Cs[(i*8+e)*260 + n]);
      *(uint4*)(op + i*8) = pk.v;
    }
  }
}

// ---------------- K2: fused attention: ctx (biased softmax @ V) + attn_w (plain) ----------
// No LDS staging (K/V are L2-resident). Pass 1 is barrier-free AND asm-free: the old
// "s_waitcnt lgkmcnt(0) + memory clobber" forbade hoisting kt+1's global loads above
// kt's waits -> every iteration exposed L2 latency. The Ps write->read ordering is
// guaranteed by per-wave in-order LDS + compiler alias analysis (same object), so the
// asm was only pinning the schedule. Explicit named-register prefetch (cK/cV/cE vs
// nK/nV/nE, all constant-indexed after unroll) makes the pipeline structural.
__global__ __attribute__((amdgpu_waves_per_eu(2, 2))) __launch_bounds__(256) void k_attn_fused(
    const u16* __restrict__ Qg, const u16* __restrict__ Kg,
    const u16* __restrict__ Vtg, const float* __restrict__ ebtab,
    u16* __restrict__ ctx, float* __restrict__ AW)
{
  __shared__ bf16_t Ps[4][16*40];          // 5120 B, wave-private
  __shared__ float  invTab[8][16];         // 512 B, one-time exchange

  const int t  = threadIdx.x;
  const int wv = t >> 6;
  const int ln = t & 15;
  const int qd = (t & 63) >> 4;
  const int lane = t & 63;
  const int b  = blockIdx.y;
  const int qt = blockIdx.x;
  const int qh_img = qt >> 1;
  const int qw0 = (qt & 1) * 16;

  const u16* Qb  = Qg  + (size_t)(b*1024 + qt*16) * 256;
  const u16* Kb  = Kg  + (size_t)b * 1024 * 256;
  const u16* Vtb = Vtg + (size_t)b * 256 * 1024;

  f32x4 z4 = {0.0f,0.0f,0.0f,0.0f};

  bf16x8 aq[2];
  aq[0] = *(const bf16x8*)(Qb + ln*256 + wv*32 + qd*8);
  aq[1] = *(const bf16x8*)(Qb + ln*256 + (wv+4)*32 + qd*8);

  float se[2][4], sb[2][4];
  #pragma unroll
  for (int hi=0;hi<2;hi++)
    #pragma unroll
    for (int r=0;r<4;r++){ se[hi][r]=0.0f; sb[hi][r]=0.0f; }

  f32x4 oacc[2][2];
  oacc[0][0]=z4; oacc[0][1]=z4; oacc[1][0]=z4; oacc[1][1]=z4;

  // current-iteration fragments (registers)
  bf16x8 cK[2][2], cV[2][2]; float cE[2];
  #pragma unroll
  for (int hi=0;hi<2;hi++){
    const int h = wv + hi*4;
    #pragma unroll
    for (int kh=0;kh<2;kh++)
      cK[hi][kh] = *(const bf16x8*)(Kb + (size_t)(kh*16 + ln)*256 + h*32 + qd*8);
    #pragma unroll
    for (int nh=0;nh<2;nh++)
      cV[hi][nh] = *(const bf16x8*)(Vtb + (size_t)(h*32 + nh*16 + ln)*1024 + qd*8);
    cE[hi] = ebtab[(size_t)(31 - qh_img)*512 + h*64 + lane];
  }

  // ---- pass 1: exp once -> both denominators + unnormalized PV. No barriers. ----
  #pragma unroll 2
  for (int kt=0; kt<32; kt++){
    bf16x8 nK[2][2], nV[2][2]; float nE[2];
    if (kt < 31){
      #pragma unroll
      for (int hi=0;hi<2;hi++){
        const int h = wv + hi*4;
        #pragma unroll
        for (int kh=0;kh<2;kh++)
          nK[hi][kh] = *(const bf16x8*)(Kb + (size_t)((kt+1)*32 + kh*16 + ln)*256 + h*32 + qd*8);
        #pragma unroll
        for (int nh=0;nh<2;nh++)
          nV[hi][nh] = *(const bf16x8*)(Vtb + (size_t)(h*32 + nh*16 + ln)*1024 + (kt+1)*32 + qd*8);
        nE[hi] = ebtab[(size_t)(kt + 1 - qh_img + 31)*512 + h*64 + lane];
      }
    }

    #pragma unroll
    for (int hi=0;hi<2;hi++){
      #pragma unroll
      for (int kh=0;kh<2;kh++){
        f32x4 sc = MFMA16(aq[hi], cK[hi][kh], z4);
        #pragma unroll
        for (int r=0;r<4;r++){
          float e  = exp2f(sc[r]);                 // Q pre-scaled by log2e/sqrt(dk)
          int idx = kh*16 + ln - (qw0 + qd*4 + r) + 31;   // dw+31 in [0,62]
          float ebv = __shfl(cE[hi], idx);
          float eb = e * ebv;
          se[hi][r] += e;
          sb[hi][r] += eb;
          Ps[wv][(qd*4+r)*40 + kh*16 + ln] = (bf16_t)eb;   // unnormalized
        }
      }
      // per-wave in-order LDS + alias-visible dependence orders Ps write->read;
      // compiler inserts the lgkmcnt wait itself.
      bf16x8 ap = *(const bf16x8*)&Ps[wv][ln*40 + qd*8];
      oacc[hi][0] = MFMA16(ap, cV[hi][0], oacc[hi][0]);
      oacc[hi][1] = MFMA16(ap, cV[hi][1], oacc[hi][1]);
    }

    if (kt < 31){
      #pragma unroll
      for (int hi=0;hi<2;hi++){
        cE[hi] = nE[hi];
        #pragma unroll
        for (int kh=0;kh<2;kh++) cK[hi][kh] = nK[hi][kh];
        #pragma unroll
        for (int nh=0;nh<2;nh++) cV[hi][nh] = nV[hi][nh];
      }
    }
  }

  // reduce denominators across the 16 column-lanes (same qd group)
  float inv_se[2][4], inv_sb[2][4];
  #pragma unroll
  for (int hi=0;hi<2;hi++)
    #pragma unroll
    for (int r=0;r<4;r++){
      float a = se[hi][r], c = sb[hi][r];
      #pragma unroll
      for (int m=1;m<16;m<<=1){ a += __shfl_xor(a, m, 16); c += __shfl_xor(c, m, 16); }
      inv_se[hi][r] = 1.0f / a;
      inv_sb[hi][r] = 1.0f / c;
    }

  // ---- one-time exchange of plain-softmax denominators across waves ----
  if (ln == 0){
    #pragma unroll
    for (int r=0;r<4;r++){
      invTab[wv][qd*4+r]   = inv_se[0][r];
      invTab[wv+4][qd*4+r] = inv_se[1][r];
    }
  }
  __syncthreads();
  float invq[8][4];
  #pragma unroll
  for (int h=0;h<8;h++)
    #pragma unroll
    for (int r=0;r<4;r++)
      invq[h][r] = invTab[h][qd*4+r];

  // Q fragments for all 8 heads (L1/L2-hot re-read; constant-indexed after unroll)
  bf16x8 aqAll[8];
  #pragma unroll
  for (int h=0;h<8;h++)
    aqAll[h] = *(const bf16x8*)(Qb + ln*256 + h*32 + qd*8);

  // ---- pass 2: plain probs -> attn_w (mean over heads). Wave owns kt-range;
  //      head-sum entirely in-register. No barriers. ----
  for (int kti=0; kti<8; kti++){
    const int kt = wv*8 + kti;
    float aw0[2][4];
    #pragma unroll
    for (int kh=0;kh<2;kh++)
      #pragma unroll
      for (int r=0;r<4;r++) aw0[kh][r] = 0.0f;

    #pragma unroll
    for (int h=0;h<8;h++){
      #pragma unroll
      for (int kh=0;kh<2;kh++){
        bf16x8 bk = *(const bf16x8*)(Kb + (size_t)(kt*32 + kh*16 + ln)*256 + h*32 + qd*8);
        f32x4 sc = MFMA16(aqAll[h], bk, z4);
        #pragma unroll
        for (int r=0;r<4;r++)
          aw0[kh][r] += exp2f(sc[r]) * invq[h][r];
      }
    }
    #pragma unroll
    for (int kh=0;kh<2;kh++)
      #pragma unroll
      for (int r=0;r<4;r++)
        AW[(size_t)(b*1024 + qt*16 + qd*4 + r)*1024 + kt*32 + kh*16 + ln]
            = aw0[kh][r] * 0.125f;
  }

  // ---- ctx out (normalize by biased denominator) ----
  #pragma unroll
  for (int hi=0;hi<2;hi++){
    const int h = wv + hi*4;
    #pragma unroll
    for (int nh=0;nh<2;nh++)
      #pragma unroll
      for (int r=0;r<4;r++)
        ctx[(size_t)(b*1024 + qt*16 + qd*4 + r)*256 + h*32 + nh*16 + ln]
            = f2bf(oacc[hi][nh][r] * inv_sb[hi][r]);
  }
}

// ---------------- K3: out = ctx@Wo^T + bo ; y = LN(out + x). f32 out. ---------------------
__global__ __attribute__((amdgpu_waves_per_eu(2, 2))) __launch_bounds__(256) void k_outln(
    const u16* __restrict__ CX, const float* __restrict__ Wo,
    const float* __restrict__ bo, const float* __restrict__ xs,
    const float* __restrict__ lgm, const float* __restrict__ lbt,
    float* __restrict__ Out)
{
  __shared__ bf16_t Cts[32*40];
  __shared__ bf16_t Wsh[256*40];
  __shared__ float  Ys[32*260];
  __shared__ float  parts[2][32][2];
  const int t = threadIdx.x;
  const int wv = t>>6, ln = t&15, qd = (t&63)>>4;
  const int wm = wv & 1, wn = wv >> 1;
  const int m0 = blockIdx.x * 32;

  f32x4 z4 = {0.0f,0.0f,0.0f,0.0f};
  f32x4 acc[8];
  #pragma unroll
  for (int i=0;i<8;i++) acc[i] = z4;

  uint2 CR; f32x4 WR[8];
  CR = *(const uint2*)(CX + (size_t)(m0 + (t>>3))*256 + (t&7)*4);
  #pragma unroll
  for (int j=0;j<8;j++)
    WR[j] = *(const f32x4*)(Wo + (size_t)((t>>3)+32*j)*256 + (t&7)*4);

  for (int kt=0; kt<8; kt++){
    __syncthreads();
    { int m = t>>3, k0 = (t&7)*4;
      *(uint2*)&Cts[m*40 + k0] = CR;
    }
    #pragma unroll
    for (int j=0;j<8;j++){
      int n = (t>>3) + 32*j, k0 = (t&7)*4;
      uint2 pk; pk.x = pack2(WR[j][0], WR[j][1]); pk.y = pack2(WR[j][2], WR[j][3]);
      *(uint2*)&Wsh[n*40 + k0] = pk;
    }
    __syncthreads();
    if (kt < 7){
      CR = *(const uint2*)(CX + (size_t)(m0 + (t>>3))*256 + (kt+1)*32 + (t&7)*4);
      #pragma unroll
      for (int j=0;j<8;j++)
        WR[j] = *(const f32x4*)(Wo + (size_t)((t>>3)+32*j)*256 + (kt+1)*32 + (t&7)*4);
    }
    bf16x8 a = *(const bf16x8*)&Cts[(wm*16+ln)*40 + qd*8];
    #pragma unroll
    for (int ni=0;ni<8;ni++){
      bf16x8 bb = *(const bf16x8*)&Wsh[(wn*128 + ni*16 + ln)*40 + qd*8];
      acc[ni] = MFMA16(a, bb, acc[ni]);
    }
  }

  float psum[4]={0,0,0,0}, psq[4]={0,0,0,0};
  #pragma unroll
  for (int ni=0;ni<8;ni++){
    const int col = wn*128 + ni*16 + ln;
    const float bias = bo[col];
    #pragma unroll
    for (int r=0;r<4;r++){
      const int row = wm*16 + qd*4 + r;
      float y = acc[ni][r] + bias + xs[(size_t)(m0+row)*256 + col];
      acc[ni][r] = y;
      psum[r] += y; psq[r] += y*y;
    }
  }
  #pragma unroll
  for (int r=0;r<4;r++){
    float a1 = psum[r], a2 = psq[r];
    #pragma unroll
    for (int m=1;m<16;m<<=1){ a1 += __shfl_xor(a1,m,16); a2 += __shfl_xor(a2,m,16); }
    if (ln == 0){
      parts[wn][wm*16 + qd*4 + r][0] = a1;
      parts[wn][wm*16 + qd*4 + r][1] = a2;
    }
  }
  __syncthreads();
  #pragma unroll
  for (int r=0;r<4;r++){
    const int row = wm*16 + qd*4 + r;
    float mu  = (parts[0][row][0] + parts[1][row][0]) * 0.00390625f;
    float var = (parts[0][row][1] + parts[1][row][1]) * 0.00390625f - mu*mu;
    float rs = rsqrtf(var + 1e-5f);
    #pragma unroll
    for (int ni=0;ni<8;ni++){
      const int col = wn*128 + ni*16 + ln;
      Ys[row*260 + col] = (acc[ni][r] - mu)*rs*lgm[col] + lbt[col];
    }
  }
  __syncthreads();
  { int row = t>>3, c0 = (t&7)*32;
    float* op = Out + (size_t)(m0+row)*256 + c0;
    #pragma unroll
    for (int i=0;i<8;i++)
      *(f32x4*)(op + 4*i) = *(const f32x4*)&Ys[row*260 + c0 + 4*i];
  }
}

// -----------------------------------------------------------------------------------------
extern "C" void kernel_launch(void* const* d_in, const int* in_sizes, int n_in,
                              void* d_out, int out_size, void* d_ws, size_t ws_size,
                              hipStream_t stream)
{
  const float* x   = (const float*)d_in[0];
  const float* wq  = (const float*)d_in[1];
  const float* bq  = (const float*)d_in[2];
  const float* wk  = (const float*)d_in[3];
  const float* bk  = (const float*)d_in[4];
  const float* wv_ = (const float*)d_in[5];
  const float* bv  = (const float*)d_in[6];
  const float* wo  = (const float*)d_in[7];
  const float* bo  = (const float*)d_in[8];
  const float* lng = (const float*)d_in[9];
  const float* lnb = (const float*)d_in[10];
  const float* dib = (const float*)d_in[11];
  const float* drb = (const float*)d_in[12];

  // ws: ebtab 128K | CX bf16 4MB | Vt bf16 4MB = 8.5 MB.
  // d_out f32: y [0, 8MB) ; attn_w [8MB, 41.5MB).
  //   Q bf16 at y bytes [0,4M), K bf16 at y bytes [4M,8M) -> dead before k_outln writes y.
  char*  ws    = (char*)d_ws;
  float* ebtab = (float*)ws;
  u16*   CX    = (u16*)(ws + 131072);
  u16*   Vt    = (u16*)(ws + 131072 + 4194304);
  float* y     = (float*)d_out;
  float* aw    = y + 2097152;
  u16*   Q     = (u16*)y;
  u16*   K     = (u16*)((char*)y + 4194304);

  const float qscale = 0.25503486f;   // log2(e)/sqrt(32) folded into Q

  k_bias_setup<<<16, 256, 0, stream>>>(dib, drb, ebtab);
  k_proj3<<<dim3(256, 3), 256, 0, stream>>>(x, wq, bq, wk, bk, wv_, bv, Q, K, Vt, qscale);
  k_attn_fused<<<dim3(64, 8), 256, 0, stream>>>(Q, K, Vt, ebtab, CX, aw);
  k_outln<<<256, 256, 0, stream>>>(CX, wo, bo, x, lng, lnb, y);  // overwrites Q,K (dead)
}